// Round 5
// baseline (50069.037 us; speedup 1.0000x reference)
//
#include <hip/hip_runtime.h>
#include <hip/hip_bf16.h>

#define NT 50
#define NB 512
#define SD 256
#define BD 1024
#define HD 1024
#define ED 1024
#define MD 256
#define NBLK 768
#define GSZ (NBLK * 256)
#define PGSZ (1024 * 256)
#define K1BIG 0x40000000

typedef __attribute__((ext_vector_type(8))) short bf16x8;
typedef __attribute__((ext_vector_type(4))) float f32x4;

__device__ __forceinline__ void gload_lds16(const void* g, void* l) {
  __builtin_amdgcn_global_load_lds(
      (const __attribute__((address_space(1))) void*)g,
      (__attribute__((address_space(3))) void*)l, 16, 0, 0);
}

__device__ __forceinline__ float sigmoidf_(float x) { return 1.0f / (1.0f + __expf(-x)); }
__device__ __forceinline__ float softplusf_(float x) {
  return (x > 0.0f) ? (x + log1pf(__expf(-x))) : log1pf(__expf(x));
}

__device__ __forceinline__ int swz(int b, int U) {  // XCD-stable unit mapping
  return (b & 7) * (U >> 3) + (b >> 3);
}

// device-scope grid barrier; each instance uses its own zero-initialized slot
__device__ __forceinline__ void gbar(unsigned* cnts, int slot) {
  __threadfence();
  __syncthreads();
  if (threadIdx.x == 0) {
    unsigned* c = cnts + slot;
    __hip_atomic_fetch_add(c, 1u, __ATOMIC_RELEASE, __HIP_MEMORY_SCOPE_AGENT);
    while (__hip_atomic_load(c, __ATOMIC_ACQUIRE, __HIP_MEMORY_SCOPE_AGENT) < (unsigned)NBLK)
      __builtin_amdgcn_s_sleep(1);
  }
  __syncthreads();
}

// wave-cooperative stage of one 64x64 bf16 tile pair (A and B) into LDS.
// asrc/wsrc are PER-LANE row pointers (already include +lane*ld and +k0).
__device__ __forceinline__ void stage64(char* dstA, char* dstB,
                                        const __hip_bfloat16* asrc,
                                        const __hip_bfloat16* wsrc, int w) {
  gload_lds16(asrc + (2 * w) * 8, dstA + (2 * w) * 1024);
  gload_lds16(asrc + (2 * w + 1) * 8, dstA + (2 * w + 1) * 1024);
  gload_lds16(wsrc + (2 * w) * 8, dstB + (2 * w) * 1024);
  gload_lds16(wsrc + (2 * w + 1) * 8, dstB + (2 * w + 1) * 1024);
}

// ---- 64x64 GEMM tile, BK=64, double-buffered LDS (R2-proven drain structure) ----
// A1: [M x K] bf16 (lda1); A2 covers global k >= K1 (lda2). Wr: weight rows
// pre-offset to this n-slice (64 rows x ldw). bias/out pre-offset to col 0..63.
// EPI: 0 fp32+bias, 1 relu->bf16+bias, 2 raw fp32 partial (no bias).
__device__ __noinline__ void gemm64(
    int EPI, char* lds,
    const __hip_bfloat16* __restrict__ A1, int lda1,
    const __hip_bfloat16* __restrict__ A2, int lda2, int K1,
    const __hip_bfloat16* __restrict__ Wr, int ldw,
    int kbase, int nIter,
    const float* __restrict__ bias,
    float* __restrict__ Cf, __hip_bfloat16* __restrict__ Cb, int ldc,
    int m0) {
  const int tid = threadIdx.x;
  const int lane = tid & 63, w = tid >> 6;
  const int wr = w >> 1, wc = w & 1;
  f32x4 acc[2][2] = {};
  const __hip_bfloat16* a1r = A1 + (size_t)(m0 + lane) * lda1;
  const __hip_bfloat16* a2r = A2 ? (A2 + (size_t)(m0 + lane) * lda2) : a1r;
  const __hip_bfloat16* wrow = Wr + (size_t)lane * ldw;

  {
    const int k0 = kbase;
    const __hip_bfloat16* as = (k0 < K1) ? (a1r + k0) : (a2r + (k0 - K1));
    stage64(lds, lds + 8192, as, wrow + k0, w);
  }
  const int kq = lane >> 4, r15 = lane & 15;
  for (int i = 0; i < nIter; ++i) {
    __syncthreads();
    if (i + 1 < nIter) {
      const int k0 = kbase + ((i + 1) << 6);
      const __hip_bfloat16* as = (k0 < K1) ? (a1r + k0) : (a2r + (k0 - K1));
      char* la = lds + (((i + 1) & 1) << 14);
      stage64(la, la + 8192, as, wrow + k0, w);
    }
    const char* la = lds + ((i & 1) << 14);
    const char* lb = la + 8192;
#pragma unroll
    for (int s = 0; s < 2; ++s) {
      bf16x8 af[2], bfr[2];
#pragma unroll
      for (int m = 0; m < 2; ++m)
        af[m] = *(const bf16x8*)(la + (size_t)((s * 4 + kq) * 64 + wr * 32 + m * 16 + r15) * 16);
#pragma unroll
      for (int n = 0; n < 2; ++n)
        bfr[n] = *(const bf16x8*)(lb + (size_t)((s * 4 + kq) * 64 + wc * 32 + n * 16 + r15) * 16);
#pragma unroll
      for (int m = 0; m < 2; ++m)
#pragma unroll
        for (int n = 0; n < 2; ++n)
          acc[m][n] = __builtin_amdgcn_mfma_f32_16x16x32_bf16(af[m], bfr[n], acc[m][n], 0, 0, 0);
    }
  }
  const int rg = lane >> 4;
#pragma unroll
  for (int m = 0; m < 2; ++m) {
#pragma unroll
    for (int n = 0; n < 2; ++n) {
      const int col = wc * 32 + n * 16 + r15;
      const float bv = (EPI == 2) ? 0.0f : bias[col];
#pragma unroll
      for (int i2 = 0; i2 < 4; ++i2) {
        const int row = m0 + wr * 32 + m * 16 + rg * 4 + i2;
        float v = acc[m][n][i2] + bv;
        if (EPI == 1) {
          v = v > 0.0f ? v : 0.0f;
          Cb[(size_t)row * ldc + col] = __float2bfloat16(v);
        } else {
          Cf[(size_t)row * ldc + col] = v;
        }
      }
    }
  }
}

struct Args {
  const float *prev_state, *actions, *prev_belief, *observations, *nonterminals,
      *me, *mp, *noise_p, *noise_q,
      *W_sa, *b_sa, *W_ih, *b_ih, *W_hh, *b_hh,
      *W_bp, *b_bp, *W_sp, *b_sp, *W_bq, *b_bq, *W_sq, *b_sq;
  float* out;
  unsigned* cnt;
  __hip_bfloat16 *Wsa, *Wih, *Whh, *Wbp, *Wbq, *Wsp, *Wsq;
  __hip_bfloat16 *actme, *obsmp, *sprev, *bel, *hid, *hpb, *hqb;
  float *gi, *gh, *hqp, *pp, *qp;
};

// ---------------- prep: weight cvt, actme pack, state init ----------------
__global__ __launch_bounds__(256) void prep(Args P) {
  const int gtid = blockIdx.x * 256 + threadIdx.x;
  for (int i = gtid; i < BD * 576; i += PGSZ) {  // W_sa padded K 544->576
    int r = i / 576, k = i - r * 576;
    P.Wsa[i] = __float2bfloat16(k < 544 ? P.W_sa[(size_t)r * 544 + k] : 0.0f);
  }
  for (int i = gtid; i < 3 * BD * BD; i += PGSZ) P.Wih[i] = __float2bfloat16(P.W_ih[i]);
  for (int i = gtid; i < 3 * BD * BD; i += PGSZ) P.Whh[i] = __float2bfloat16(P.W_hh[i]);
  for (int i = gtid; i < HD * BD; i += PGSZ) P.Wbp[i] = __float2bfloat16(P.W_bp[i]);
  for (int i = gtid; i < HD * 2304; i += PGSZ) P.Wbq[i] = __float2bfloat16(P.W_bq[i]);
  for (int i = gtid; i < 512 * HD; i += PGSZ) P.Wsp[i] = __float2bfloat16(P.W_sp[i]);
  for (int i = gtid; i < 512 * HD; i += PGSZ) P.Wsq[i] = __float2bfloat16(P.W_sq[i]);
  for (int i = gtid; i < NT * NB * 320; i += PGSZ) {  // [act(32)|me(256)|pad(32)]
    int tb = i / 320, j = i - tb * 320;
    float v = (j < 32) ? P.actions[(size_t)tb * 32 + j]
                       : (j < 288 ? P.me[(size_t)tb * 256 + (j - 32)] : 0.0f);
    P.actme[i] = __float2bfloat16(v);
  }
  for (int i = gtid; i < NB * SD; i += PGSZ) {
    int r = i >> 8;
    P.sprev[i] = __float2bfloat16(P.prev_state[i] * P.nonterminals[r]);
  }
  for (int i = gtid; i < NB * BD; i += PGSZ) P.bel[i] = __float2bfloat16(P.prev_belief[i]);
}

// ---------------- mega: all 50 steps, grid-resident ----------------
__global__ __launch_bounds__(256, 4) void mega(Args P) {
  __shared__ alignas(16) char lds[32768];
  const int b = blockIdx.x, tid = threadIdx.x;
  const int gtid = b * 256 + tid;

  const size_t o_ps = (size_t)NT * NB * BD;
  const size_t blk = (size_t)NT * NB * SD;

  for (int t = 0; t < NT; ++t) {
    const int s0 = t * 7;
    // ---- A: hid = relu([sprev | actme] @ Wsa^T + b_sa), K padded to 576 ----
    if (b < 128) {
      const int u = swz(b, 128), n = u >> 3, m = u & 7;
      gemm64(1, lds, P.sprev, SD, P.actme + (size_t)t * NB * 320, 320, 256,
             P.Wsa + (size_t)n * 64 * 576, 576, 0, 9,
             P.b_sa + n * 64, nullptr, P.hid + n * 64, BD, m * 64);
    }
    gbar(P.cnt, s0 + 0);
    // ---- B: gi = hid@Wih^T+b_ih ; gh = bel@Whh^T+b_hh (768 tiles exactly) ----
    {
      const int u = swz(b, 768), n = u >> 3, m = u & 7;
      if (n < 48)
        gemm64(0, lds, P.hid, BD, nullptr, 0, K1BIG,
               P.Wih + (size_t)n * 64 * BD, BD, 0, 16,
               P.b_ih + n * 64, P.gi + n * 64, nullptr, 3 * BD, m * 64);
      else
        gemm64(0, lds, P.bel, BD, nullptr, 0, K1BIG,
               P.Whh + (size_t)(n - 48) * 64 * BD, BD, 0, 16,
               P.b_hh + (n - 48) * 64, P.gh + (n - 48) * 64, nullptr, 3 * BD, m * 64);
    }
    gbar(P.cnt, s0 + 1);
    // ---- C: GRU pointwise + obs/mp bf16 pack ----
    {
      const float* hpre = (t == 0) ? P.prev_belief : (P.out + (size_t)(t - 1) * NB * BD);
      for (int i = gtid; i < NB * 2304; i += GSZ) {
        int bb = i / 2304, j = i - bb * 2304;
        if (j < BD) {
          const float* gib = P.gi + (size_t)bb * 3072;
          const float* ghb = P.gh + (size_t)bb * 3072;
          float r_ = sigmoidf_(gib[j] + ghb[j]);
          float z_ = sigmoidf_(gib[j + 1024] + ghb[j + 1024]);
          float n_ = tanhf(gib[j + 2048] + r_ * ghb[j + 2048]);
          float bel = (1.0f - z_) * n_ + z_ * hpre[(size_t)bb * BD + j];
          P.out[(size_t)t * NB * BD + (size_t)bb * BD + j] = bel;
          P.bel[(size_t)bb * BD + j] = __float2bfloat16(bel);
        } else {
          int jj = j - BD;
          float v = (jj < ED) ? P.observations[(size_t)t * NB * ED + (size_t)bb * ED + jj]
                              : P.mp[(size_t)t * NB * MD + (size_t)bb * MD + (jj - ED)];
          P.obsmp[(size_t)bb * 1280 + jj] = __float2bfloat16(v);
        }
      }
    }
    gbar(P.cnt, s0 + 2);
    // ---- D: hp direct (relu->bf16); hq split-K3 fp32 partials ----
    if (b < 512) {
      const int u = swz(b, 512);
      if (u < 128) {
        const int n = u >> 3, m = u & 7;
        gemm64(1, lds, P.bel, BD, nullptr, 0, K1BIG,
               P.Wbp + (size_t)n * 64 * BD, BD, 0, 16,
               P.b_bp + n * 64, nullptr, P.hpb + n * 64, HD, m * 64);
      } else {
        const int e = u - 128;
        const int n = e / 24, rem = e - n * 24, m = rem / 3, ks = rem - m * 3;
        gemm64(2, lds, P.bel, BD, P.obsmp, 1280, 1024,
               P.Wbq + (size_t)n * 64 * 2304, 2304, ks * 768, 12,
               nullptr, P.hqp + (size_t)ks * NB * HD + n * 64, nullptr, HD, m * 64);
      }
    }
    gbar(P.cnt, s0 + 3);
    // ---- D2: hq = relu(sum partials + b_bq) -> bf16 ----
    for (int i = gtid; i < NB * HD; i += GSZ) {
      int c = i & 1023;
      float v = P.hqp[i] + P.hqp[NB * HD + i] + P.hqp[2 * NB * HD + i] + P.b_bq[c];
      P.hqb[i] = __float2bfloat16(v > 0.0f ? v : 0.0f);
    }
    gbar(P.cnt, s0 + 4);
    // ---- E: p/q head GEMMs, split-K2 fp32 partials (no bias) ----
    if (b < 256) {
      const int u = swz(b, 256), pq = u >> 7, r = u & 127;
      const int n = r >> 4, kh = (r >> 3) & 1, m = r & 7;
      const __hip_bfloat16* Aop = (pq ? P.hqb : P.hpb) + kh * 512;
      const __hip_bfloat16* Wop = (pq ? P.Wsq : P.Wsp) + (size_t)n * 64 * BD + kh * 512;
      float* Oop = (pq ? P.qp : P.pp) + (size_t)kh * NB * 512 + n * 64;
      gemm64(2, lds, Aop, BD, nullptr, 0, K1BIG, Wop, BD, 0, 8,
             nullptr, Oop, nullptr, 512, m * 64);
    }
    gbar(P.cnt, s0 + 5);
    // ---- F: head math -> d_out + next-step sprev carry ----
    {
      const float* ntn = P.nonterminals + (size_t)((t + 1 < NT) ? t + 1 : t) * NB;
      for (int i = gtid; i < NB * SD; i += GSZ) {
        int r = i >> 8, j = i & 255;
        const size_t ro = (size_t)r * 512;
        float pm = P.pp[ro + j] + P.pp[NB * 512 + ro + j] + P.b_sp[j];
        float pr_ = P.pp[ro + 256 + j] + P.pp[NB * 512 + ro + 256 + j] + P.b_sp[256 + j];
        float pstd = fminf(softplusf_(pr_) + 0.1f, 5.0f);
        float ps = pm + pstd * P.noise_p[(size_t)t * NB * SD + i];
        float qm = P.qp[ro + j] + P.qp[NB * 512 + ro + j] + P.b_sq[j];
        float qr_ = P.qp[ro + 256 + j] + P.qp[NB * 512 + ro + 256 + j] + P.b_sq[256 + j];
        float qstd = fminf(softplusf_(qr_) + 0.1f, 5.0f);
        float qs = qm + qstd * P.noise_q[(size_t)t * NB * SD + i];
        float* o = P.out + o_ps + (size_t)t * NB * SD + i;
        o[0] = ps; o[blk] = pm; o[2 * blk] = pstd;
        o[3 * blk] = qs; o[4 * blk] = qm; o[5 * blk] = qstd;
        P.sprev[i] = __float2bfloat16(qs * ntn[r]);
      }
    }
    gbar(P.cnt, s0 + 6);
  }
}

// ---------------- host ----------------

extern "C" void kernel_launch(void* const* d_in, const int* in_sizes, int n_in,
                              void* d_out, int out_size, void* d_ws, size_t ws_size,
                              hipStream_t stream) {
  Args P;
  P.prev_state = (const float*)d_in[0];
  P.actions = (const float*)d_in[1];
  P.prev_belief = (const float*)d_in[2];
  P.observations = (const float*)d_in[3];
  P.nonterminals = (const float*)d_in[4];
  P.me = (const float*)d_in[5];
  P.mp = (const float*)d_in[6];
  P.noise_p = (const float*)d_in[7];
  P.noise_q = (const float*)d_in[8];
  P.W_sa = (const float*)d_in[9];  P.b_sa = (const float*)d_in[10];
  P.W_ih = (const float*)d_in[11]; P.b_ih = (const float*)d_in[12];
  P.W_hh = (const float*)d_in[13]; P.b_hh = (const float*)d_in[14];
  P.W_bp = (const float*)d_in[15]; P.b_bp = (const float*)d_in[16];
  P.W_sp = (const float*)d_in[17]; P.b_sp = (const float*)d_in[18];
  P.W_bq = (const float*)d_in[19]; P.b_bq = (const float*)d_in[20];
  P.W_sq = (const float*)d_in[21]; P.b_sq = (const float*)d_in[22];
  P.out = (float*)d_out;

  char* p = (char*)d_ws;
  auto carve = [&](size_t bytes) -> char* {
    char* r = p;
    p += (bytes + 255) & ~(size_t)255;
    return r;
  };
  P.cnt = (unsigned*)carve(4096);
  P.Wsa = (__hip_bfloat16*)carve((size_t)BD * 576 * 2);
  P.Wih = (__hip_bfloat16*)carve((size_t)3 * BD * BD * 2);
  P.Whh = (__hip_bfloat16*)carve((size_t)3 * BD * BD * 2);
  P.Wbp = (__hip_bfloat16*)carve((size_t)HD * BD * 2);
  P.Wbq = (__hip_bfloat16*)carve((size_t)HD * 2304 * 2);
  P.Wsp = (__hip_bfloat16*)carve((size_t)512 * HD * 2);
  P.Wsq = (__hip_bfloat16*)carve((size_t)512 * HD * 2);
  P.actme = (__hip_bfloat16*)carve((size_t)NT * NB * 320 * 2);
  P.obsmp = (__hip_bfloat16*)carve((size_t)NB * 1280 * 2);
  P.sprev = (__hip_bfloat16*)carve((size_t)NB * SD * 2);
  P.bel = (__hip_bfloat16*)carve((size_t)NB * BD * 2);
  P.hid = (__hip_bfloat16*)carve((size_t)NB * BD * 2);
  P.hpb = (__hip_bfloat16*)carve((size_t)NB * HD * 2);
  P.hqb = (__hip_bfloat16*)carve((size_t)NB * HD * 2);
  P.gi = (float*)carve((size_t)NB * 3 * BD * 4);
  P.gh = (float*)carve((size_t)NB * 3 * BD * 4);
  P.hqp = (float*)carve((size_t)3 * NB * HD * 4);
  P.pp = (float*)carve((size_t)2 * NB * 512 * 4);
  P.qp = (float*)carve((size_t)2 * NB * 512 * 4);

  hipMemsetAsync(P.cnt, 0, 4096, stream);
  prep<<<1024, 256, 0, stream>>>(P);
  mega<<<NBLK, 256, 0, stream>>>(P);
}

// Round 6
// 6712.942 us; speedup vs baseline: 7.4586x; 7.4586x over previous
//
#include <hip/hip_runtime.h>
#include <hip/hip_bf16.h>

#define NT 50
#define NB 512
#define SD 256
#define BD 1024
#define HD 1024
#define ED 1024
#define MD 256
#define NBLK 768
#define GSZ (NBLK * 256)
#define PGSZ (1024 * 256)
#define K1BIG 0x40000000
#define NSLOT 256

typedef __attribute__((ext_vector_type(8))) short bf16x8;
typedef __attribute__((ext_vector_type(4))) float f32x4;

__device__ __forceinline__ void gload_lds16(const void* g, void* l) {
  __builtin_amdgcn_global_load_lds(
      (const __attribute__((address_space(1))) void*)g,
      (__attribute__((address_space(3))) void*)l, 16, 0, 0);
}

// ---- coherent (device-scope, cache-bypassing) access helpers ----
__device__ __forceinline__ f32x4 cload16(const void* a) {
  f32x4 t;
  asm volatile("global_load_dwordx4 %0, %1, off sc0 sc1\n\ts_waitcnt vmcnt(0)"
               : "=&v"(t) : "v"(a) : "memory");
  return t;
}
__device__ __forceinline__ void cload2x16(const void* a0, const void* a1, f32x4* r0, f32x4* r1) {
  f32x4 t0, t1;
  asm volatile("global_load_dwordx4 %0, %2, off sc0 sc1\n\t"
               "global_load_dwordx4 %1, %3, off sc0 sc1\n\t"
               "s_waitcnt vmcnt(0)"
               : "=&v"(t0), "=&v"(t1) : "v"(a0), "v"(a1) : "memory");
  *r0 = t0; *r1 = t1;
}
__device__ __forceinline__ void cstore16(void* g, f32x4 v) {
  asm volatile("global_store_dwordx4 %0, %1, off sc0 sc1" :: "v"(g), "v"(v) : "memory");
}
__device__ __forceinline__ void cstore4(void* g, float v) {
  asm volatile("global_store_dword %0, %1, off sc0 sc1" :: "v"(g), "v"(v) : "memory");
}
__device__ __forceinline__ void cstore2(void* g, unsigned v) {
  asm volatile("global_store_short %0, %1, off sc0 sc1" :: "v"(g), "v"(v) : "memory");
}

__device__ __forceinline__ float sigmoidf_(float x) { return 1.0f / (1.0f + __expf(-x)); }
__device__ __forceinline__ float softplusf_(float x) {
  return (x > 0.0f) ? (x + log1pf(__expf(-x))) : log1pf(__expf(x));
}
__device__ __forceinline__ unsigned short bfb(float x) {
  __hip_bfloat16 h = __float2bfloat16(x);
  return __builtin_bit_cast(unsigned short, h);
}

// ---- fence-free hierarchical grid barrier (relaxed atomics only) ----
// layout (words): loc[slot*128 + xcd*16], glob[32768 + slot*16], flag[36864 + slot*16]
__device__ __forceinline__ void gbar(unsigned* cnt, int slot, int b) {
  asm volatile("s_waitcnt vmcnt(0) lgkmcnt(0)" ::: "memory");
  __syncthreads();
  if (threadIdx.x == 0) {
    unsigned* lc = cnt + slot * 128 + (b & 7) * 16;
    unsigned* gc = cnt + NSLOT * 128 + slot * 16;
    unsigned* fl = cnt + NSLOT * 144 + slot * 16;
    unsigned old = __hip_atomic_fetch_add(lc, 1u, __ATOMIC_RELAXED, __HIP_MEMORY_SCOPE_AGENT);
    if (old == (NBLK / 8 - 1)) {
      unsigned g = __hip_atomic_fetch_add(gc, 1u, __ATOMIC_RELAXED, __HIP_MEMORY_SCOPE_AGENT);
      if (g == 7u)
        __hip_atomic_store(fl, 1u, __ATOMIC_RELAXED, __HIP_MEMORY_SCOPE_AGENT);
    }
    while (__hip_atomic_load(fl, __ATOMIC_RELAXED, __HIP_MEMORY_SCOPE_AGENT) == 0u)
      __builtin_amdgcn_s_sleep(16);
  }
  __syncthreads();
}

// ---- 64x64 GEMM tile, BK=64, dbuf LDS. A staged COHERENTLY (reg->LDS);
// W staged via global_load_lds (plain cached -> stays L2-resident).
// EPI: 0 = fp32+bias coherent out, 1 = relu->bf16+bias coherent out.
__device__ __noinline__ void gemm64(
    int EPI, char* lds,
    const __hip_bfloat16* __restrict__ A1, int lda1,
    const __hip_bfloat16* __restrict__ A2, int lda2, int K1,
    const __hip_bfloat16* __restrict__ Wr, int ldw, int nIter,
    const float* __restrict__ bias,
    float* __restrict__ Cf, __hip_bfloat16* __restrict__ Cb, int ldc, int m0) {
  const int tid = threadIdx.x;
  const int lane = tid & 63, w = tid >> 6;
  const int wr = w >> 1, wc = w & 1;
  f32x4 acc[2][2] = {};
  const __hip_bfloat16* a1r = A1 + (size_t)(m0 + lane) * lda1;
  const __hip_bfloat16* a2r = A2 ? (A2 + (size_t)(m0 + lane) * lda2) : a1r;
  const __hip_bfloat16* wrow = Wr + (size_t)lane * ldw;

  auto stage = [&](int buf, int it) {
    const int k0 = it << 6;
    char* la = lds + (buf << 14);
    char* lb = la + 8192;
    const __hip_bfloat16* as = (k0 < K1) ? (a1r + k0) : (a2r + (k0 - K1));
    f32x4 r0, r1;
    cload2x16(as + (2 * w) * 8, as + (2 * w + 1) * 8, &r0, &r1);
    *(f32x4*)(la + (2 * w) * 1024 + lane * 16) = r0;
    *(f32x4*)(la + (2 * w + 1) * 1024 + lane * 16) = r1;
    gload_lds16(wrow + k0 + (2 * w) * 8, lb + (2 * w) * 1024);
    gload_lds16(wrow + k0 + (2 * w + 1) * 8, lb + (2 * w + 1) * 1024);
  };

  stage(0, 0);
  const int kq = lane >> 4, r15 = lane & 15;
  for (int i = 0; i < nIter; ++i) {
    __syncthreads();
    if (i + 1 < nIter) stage((i + 1) & 1, i + 1);
    const char* la = lds + ((i & 1) << 14);
    const char* lb = la + 8192;
#pragma unroll
    for (int s = 0; s < 2; ++s) {
      bf16x8 af[2], bfr[2];
#pragma unroll
      for (int m = 0; m < 2; ++m)
        af[m] = *(const bf16x8*)(la + (size_t)((s * 4 + kq) * 64 + wr * 32 + m * 16 + r15) * 16);
#pragma unroll
      for (int n = 0; n < 2; ++n)
        bfr[n] = *(const bf16x8*)(lb + (size_t)((s * 4 + kq) * 64 + wc * 32 + n * 16 + r15) * 16);
#pragma unroll
      for (int m = 0; m < 2; ++m)
#pragma unroll
        for (int n = 0; n < 2; ++n)
          acc[m][n] = __builtin_amdgcn_mfma_f32_16x16x32_bf16(af[m], bfr[n], acc[m][n], 0, 0, 0);
    }
  }
  const int rg = lane >> 4;
#pragma unroll
  for (int m = 0; m < 2; ++m) {
#pragma unroll
    for (int n = 0; n < 2; ++n) {
      const int col = wc * 32 + n * 16 + r15;
      const float bv = bias[col];
#pragma unroll
      for (int i2 = 0; i2 < 4; ++i2) {
        const int row = m0 + wr * 32 + m * 16 + rg * 4 + i2;
        float v = acc[m][n][i2] + bv;
        if (EPI == 1) {
          v = v > 0.0f ? v : 0.0f;
          cstore2(Cb + (size_t)row * ldc + col, (unsigned)bfb(v));
        } else {
          cstore4(Cf + (size_t)row * ldc + col, v);
        }
      }
    }
  }
}

// ---- head GEMM (K=1024) with fused prior/posterior epilogue; W pre-interleaved ----
__device__ __noinline__ void gemm_head64(
    char* lds, const __hip_bfloat16* __restrict__ A,
    const __hip_bfloat16* __restrict__ Wr, const float* __restrict__ bias,
    const float* __restrict__ noise, float* __restrict__ st_o, float* __restrict__ mn_o,
    float* __restrict__ sd_o, const float* __restrict__ ntn,
    __hip_bfloat16* __restrict__ sprev, int isq, int n0, int m0) {
  const int tid = threadIdx.x;
  const int lane = tid & 63, w = tid >> 6;
  const int wr = w >> 1, wc = w & 1;
  f32x4 acc[2][2] = {};
  const __hip_bfloat16* ar = A + (size_t)(m0 + lane) * BD;
  const __hip_bfloat16* wrow = Wr + (size_t)lane * BD;

  auto stage = [&](int buf, int it) {
    const int k0 = it << 6;
    char* la = lds + (buf << 14);
    char* lb = la + 8192;
    f32x4 r0, r1;
    cload2x16(ar + k0 + (2 * w) * 8, ar + k0 + (2 * w + 1) * 8, &r0, &r1);
    *(f32x4*)(la + (2 * w) * 1024 + lane * 16) = r0;
    *(f32x4*)(la + (2 * w + 1) * 1024 + lane * 16) = r1;
    gload_lds16(wrow + k0 + (2 * w) * 8, lb + (2 * w) * 1024);
    gload_lds16(wrow + k0 + (2 * w + 1) * 8, lb + (2 * w + 1) * 1024);
  };

  stage(0, 0);
  const int kq = lane >> 4, r15 = lane & 15;
  for (int i = 0; i < 16; ++i) {
    __syncthreads();
    if (i + 1 < 16) stage((i + 1) & 1, i + 1);
    const char* la = lds + ((i & 1) << 14);
    const char* lb = la + 8192;
#pragma unroll
    for (int s = 0; s < 2; ++s) {
      bf16x8 af[2], bfr[2];
#pragma unroll
      for (int m = 0; m < 2; ++m)
        af[m] = *(const bf16x8*)(la + (size_t)((s * 4 + kq) * 64 + wr * 32 + m * 16 + r15) * 16);
#pragma unroll
      for (int n = 0; n < 2; ++n)
        bfr[n] = *(const bf16x8*)(lb + (size_t)((s * 4 + kq) * 64 + wc * 32 + n * 16 + r15) * 16);
#pragma unroll
      for (int m = 0; m < 2; ++m)
#pragma unroll
        for (int n = 0; n < 2; ++n)
          acc[m][n] = __builtin_amdgcn_mfma_f32_16x16x32_bf16(af[m], bfr[n], acc[m][n], 0, 0, 0);
    }
  }
  const int rg = lane >> 4;
  const bool even = (r15 & 1) == 0;
#pragma unroll
  for (int m = 0; m < 2; ++m) {
#pragma unroll
    for (int n = 0; n < 2; ++n) {
      const int col = n0 + wc * 32 + n * 16 + r15;  // 0..511 interleaved mean/raw
      const int j = col >> 1;
      const float bv = bias[col];
#pragma unroll
      for (int i2 = 0; i2 < 4; ++i2) {
        const int row = m0 + wr * 32 + m * 16 + rg * 4 + i2;
        float v = acc[m][n][i2] + bv;
        float partner = __shfl_xor(v, 1);
        float mean = even ? v : partner;
        float raw = even ? partner : v;
        float sd = fminf(softplusf_(raw) + 0.1f, 5.0f);
        const size_t o = (size_t)row * SD + j;
        if (even) {
          float st = mean + sd * noise[o];
          mn_o[o] = mean;
          st_o[o] = st;
          if (isq) cstore2(sprev + o, (unsigned)bfb(st * ntn[row]));
        } else {
          sd_o[o] = sd;
        }
      }
    }
  }
}

struct Args {
  const float *prev_state, *actions, *prev_belief, *observations, *nonterminals,
      *me, *mp, *noise_p, *noise_q,
      *W_sa, *b_sa, *W_ih, *b_ih, *W_hh, *b_hh,
      *W_bp, *b_bp, *W_sp, *b_sp, *W_bq, *b_bq, *W_sq, *b_sq;
  float* out;
  unsigned* cnt;
  __hip_bfloat16 *Wsa, *Wih, *Whh, *Wbp, *Wbq, *Wsp, *Wsq;
  __hip_bfloat16 *actme, *obsmp, *sprev, *bel, *hid, *hpb, *hqb;
  float *gi, *gh;
  float *bsp_ro, *bsq_ro;
};

// ---------------- prep: weight cvt (+ head interleave), actme pack, state init ----------------
__global__ __launch_bounds__(256) void prep(Args P) {
  const int gtid = blockIdx.x * 256 + threadIdx.x;
  for (int i = gtid; i < BD * 576; i += PGSZ) {  // W_sa padded K 544->576
    int r = i / 576, k = i - r * 576;
    P.Wsa[i] = __float2bfloat16(k < 544 ? P.W_sa[(size_t)r * 544 + k] : 0.0f);
  }
  for (int i = gtid; i < 3 * BD * BD; i += PGSZ) P.Wih[i] = __float2bfloat16(P.W_ih[i]);
  for (int i = gtid; i < 3 * BD * BD; i += PGSZ) P.Whh[i] = __float2bfloat16(P.W_hh[i]);
  for (int i = gtid; i < HD * BD; i += PGSZ) P.Wbp[i] = __float2bfloat16(P.W_bp[i]);
  for (int i = gtid; i < HD * 2304; i += PGSZ) P.Wbq[i] = __float2bfloat16(P.W_bq[i]);
  for (int i = gtid; i < 512 * HD; i += PGSZ) {  // interleave: row r -> 2r / 2(r-256)+1
    int r = i >> 10, k = i & 1023;
    int dr = (r < 256) ? (2 * r) : (2 * (r - 256) + 1);
    P.Wsp[(size_t)dr * 1024 + k] = __float2bfloat16(P.W_sp[i]);
    P.Wsq[(size_t)dr * 1024 + k] = __float2bfloat16(P.W_sq[i]);
  }
  for (int i = gtid; i < 512; i += PGSZ) {
    int dr = (i < 256) ? (2 * i) : (2 * (i - 256) + 1);
    P.bsp_ro[dr] = P.b_sp[i];
    P.bsq_ro[dr] = P.b_sq[i];
  }
  for (int i = gtid; i < NT * NB * 320; i += PGSZ) {  // [act(32)|me(256)|pad(32)]
    int tb = i / 320, j = i - tb * 320;
    float v = (j < 32) ? P.actions[(size_t)tb * 32 + j]
                       : (j < 288 ? P.me[(size_t)tb * 256 + (j - 32)] : 0.0f);
    P.actme[i] = __float2bfloat16(v);
  }
  for (int i = gtid; i < NB * SD; i += PGSZ) {
    int r = i >> 8;
    P.sprev[i] = __float2bfloat16(P.prev_state[i] * P.nonterminals[r]);
  }
  for (int i = gtid; i < NB * BD; i += PGSZ) P.bel[i] = __float2bfloat16(P.prev_belief[i]);
}

// ---------------- mega: all 50 steps, grid-resident, fence-free ----------------
__global__ __launch_bounds__(256, 4) void mega(Args P) {
  __shared__ alignas(16) char lds[32768];
  const int b = blockIdx.x, tid = threadIdx.x;
  const int gtid = b * 256 + tid;

  const size_t o_ps = (size_t)NT * NB * BD;
  const size_t blk = (size_t)NT * NB * SD;

  for (int t = 0; t < NT; ++t) {
    const int s0 = t * 5;
    // ---- A: hid = relu([sprev|actme]@Wsa^T) (128 tiles) ; gh = bel@Whh^T (384) ----
    if (b >= 512 && b < 640) {
      const int u = (b & 7) * 16 + ((b - 512) >> 3), n = u >> 3, m = u & 7;
      gemm64(1, lds, P.sprev, SD, P.actme + (size_t)t * NB * 320, 320, 256,
             P.Wsa + (size_t)n * 64 * 576, 576, 9,
             P.b_sa + n * 64, nullptr, P.hid + n * 64, BD, m * 64);
    } else if (b >= 128 && b < 512) {
      const int u = (b & 7) * 48 + ((b - 128) >> 3), n = u >> 3, m = u & 7;
      gemm64(0, lds, P.bel, BD, nullptr, 0, K1BIG,
             P.Whh + (size_t)n * 64 * BD, BD, 16,
             P.b_hh + n * 64, P.gh + n * 64, nullptr, 3 * BD, m * 64);
    }
    gbar(P.cnt, s0 + 0, b);
    // ---- B: gi = hid@Wih^T (384 tiles) ----
    if (b < 384) {
      const int u = (b & 7) * 48 + (b >> 3), n = u >> 3, m = u & 7;
      gemm64(0, lds, P.hid, BD, nullptr, 0, K1BIG,
             P.Wih + (size_t)n * 64 * BD, BD, 16,
             P.b_ih + n * 64, P.gi + n * 64, nullptr, 3 * BD, m * 64);
    }
    gbar(P.cnt, s0 + 1, b);
    // ---- C: GRU pointwise (8 elems/thread) + obs/mp pack ----
    if (gtid < 65536) {
      const int bb = gtid >> 7, j0 = (gtid & 127) << 3;
      const float* gib = P.gi + (size_t)bb * 3072 + j0;
      const float* ghb = P.gh + (size_t)bb * 3072 + j0;
      f32x4 ir0, ir1, iz0, iz1, in0, in1, hr0, hr1, hz0, hz1, hn0, hn1;
      cload2x16(gib, gib + 4, &ir0, &ir1);
      cload2x16(gib + 1024, gib + 1028, &iz0, &iz1);
      cload2x16(gib + 2048, gib + 2052, &in0, &in1);
      cload2x16(ghb, ghb + 4, &hr0, &hr1);
      cload2x16(ghb + 1024, ghb + 1028, &hz0, &hz1);
      cload2x16(ghb + 2048, ghb + 2052, &hn0, &hn1);
      bf16x8 hb = __builtin_bit_cast(bf16x8, cload16(P.bel + (size_t)bb * BD + j0));
      float o[8];
      unsigned short nb[8];
#pragma unroll
      for (int k = 0; k < 8; ++k) {
        float gr = (k < 4 ? ir0[k] : ir1[k - 4]) + (k < 4 ? hr0[k] : hr1[k - 4]);
        float gz = (k < 4 ? iz0[k] : iz1[k - 4]) + (k < 4 ? hz0[k] : hz1[k - 4]);
        float hn = (k < 4 ? hn0[k] : hn1[k - 4]);
        float in_ = (k < 4 ? in0[k] : in1[k - 4]);
        float r_ = sigmoidf_(gr);
        float z_ = sigmoidf_(gz);
        float n_ = tanhf(in_ + r_ * hn);
        __hip_bfloat16 hv16 = __builtin_bit_cast(__hip_bfloat16, (unsigned short)hb[k]);
        float hv = __bfloat162float(hv16);
        float bel = (1.0f - z_) * n_ + z_ * hv;
        o[k] = bel;
        nb[k] = bfb(bel);
      }
      float* ob = P.out + (size_t)t * NB * BD + (size_t)bb * BD + j0;
      *(f32x4*)ob = f32x4{o[0], o[1], o[2], o[3]};
      *(f32x4*)(ob + 4) = f32x4{o[4], o[5], o[6], o[7]};
      cstore16(P.bel + (size_t)bb * BD + j0, __builtin_bit_cast(f32x4, *(bf16x8*)nb));
    } else if (gtid < 65536 + 81920) {
      const int k = gtid - 65536;
      const int bb = k / 160, rr = k - bb * 160, j0 = rr << 3;
      const float* src = (j0 < ED) ? (P.observations + (size_t)t * NB * ED + (size_t)bb * ED + j0)
                                   : (P.mp + (size_t)t * NB * MD + (size_t)bb * MD + (j0 - ED));
      f32x4 v0 = *(const f32x4*)src;
      f32x4 v1 = *(const f32x4*)(src + 4);
      unsigned short nb[8];
#pragma unroll
      for (int kk = 0; kk < 4; ++kk) { nb[kk] = bfb(v0[kk]); nb[kk + 4] = bfb(v1[kk]); }
      cstore16(P.obsmp + (size_t)bb * 1280 + j0, __builtin_bit_cast(f32x4, *(bf16x8*)nb));
    }
    gbar(P.cnt, s0 + 2, b);
    // ---- D: hp = relu(bel@Wbp^T) (128 tiles); hq = relu([bel|obsmp]@Wbq^T) (128, K=2304) ----
    if (b < 128) {
      const int u = (b & 7) * 16 + (b >> 3), n = u >> 3, m = u & 7;
      gemm64(1, lds, P.bel, BD, nullptr, 0, K1BIG,
             P.Wbp + (size_t)n * 64 * BD, BD, 16,
             P.b_bp + n * 64, nullptr, P.hpb + n * 64, HD, m * 64);
    } else if (b < 256) {
      const int u = (b & 7) * 16 + ((b - 128) >> 3), n = u >> 3, m = u & 7;
      gemm64(1, lds, P.bel, BD, P.obsmp, 1280, 1024,
             P.Wbq + (size_t)n * 64 * 2304, 2304, 36,
             P.b_bq + n * 64, nullptr, P.hqb + n * 64, HD, m * 64);
    }
    gbar(P.cnt, s0 + 3, b);
    // ---- E(+F): p/q head GEMMs with fused softplus/state epilogue + sprev carry ----
    if (b < 128) {
      const int u = (b & 7) * 16 + (b >> 3);
      const int pq = u >> 6, rr = u & 63, n = rr >> 3, m = rr & 7;
      const float* ntn = P.nonterminals + (size_t)((t + 1 < NT) ? t + 1 : t) * NB;
      const size_t to = (size_t)t * NB * SD;
      if (pq == 0)
        gemm_head64(lds, P.hpb, P.Wsp + (size_t)n * 64 * BD, P.bsp_ro,
                    P.noise_p + to, P.out + o_ps + to, P.out + o_ps + blk + to,
                    P.out + o_ps + 2 * blk + to, ntn, P.sprev, 0, n * 64, m * 64);
      else
        gemm_head64(lds, P.hqb, P.Wsq + (size_t)n * 64 * BD, P.bsq_ro,
                    P.noise_q + to, P.out + o_ps + 3 * blk + to, P.out + o_ps + 4 * blk + to,
                    P.out + o_ps + 5 * blk + to, ntn, P.sprev, 1, n * 64, m * 64);
    }
    gbar(P.cnt, s0 + 4, b);
  }
}

// ---------------- host ----------------

extern "C" void kernel_launch(void* const* d_in, const int* in_sizes, int n_in,
                              void* d_out, int out_size, void* d_ws, size_t ws_size,
                              hipStream_t stream) {
  Args P;
  P.prev_state = (const float*)d_in[0];
  P.actions = (const float*)d_in[1];
  P.prev_belief = (const float*)d_in[2];
  P.observations = (const float*)d_in[3];
  P.nonterminals = (const float*)d_in[4];
  P.me = (const float*)d_in[5];
  P.mp = (const float*)d_in[6];
  P.noise_p = (const float*)d_in[7];
  P.noise_q = (const float*)d_in[8];
  P.W_sa = (const float*)d_in[9];  P.b_sa = (const float*)d_in[10];
  P.W_ih = (const float*)d_in[11]; P.b_ih = (const float*)d_in[12];
  P.W_hh = (const float*)d_in[13]; P.b_hh = (const float*)d_in[14];
  P.W_bp = (const float*)d_in[15]; P.b_bp = (const float*)d_in[16];
  P.W_sp = (const float*)d_in[17]; P.b_sp = (const float*)d_in[18];
  P.W_bq = (const float*)d_in[19]; P.b_bq = (const float*)d_in[20];
  P.W_sq = (const float*)d_in[21]; P.b_sq = (const float*)d_in[22];
  P.out = (float*)d_out;

  char* p = (char*)d_ws;
  auto carve = [&](size_t bytes) -> char* {
    char* r = p;
    p += (bytes + 255) & ~(size_t)255;
    return r;
  };
  const size_t cnt_bytes = (size_t)NSLOT * 160 * 4;  // 160 words per slot
  P.cnt = (unsigned*)carve(cnt_bytes);
  P.Wsa = (__hip_bfloat16*)carve((size_t)BD * 576 * 2);
  P.Wih = (__hip_bfloat16*)carve((size_t)3 * BD * BD * 2);
  P.Whh = (__hip_bfloat16*)carve((size_t)3 * BD * BD * 2);
  P.Wbp = (__hip_bfloat16*)carve((size_t)HD * BD * 2);
  P.Wbq = (__hip_bfloat16*)carve((size_t)HD * 2304 * 2);
  P.Wsp = (__hip_bfloat16*)carve((size_t)512 * HD * 2);
  P.Wsq = (__hip_bfloat16*)carve((size_t)512 * HD * 2);
  P.bsp_ro = (float*)carve(512 * 4);
  P.bsq_ro = (float*)carve(512 * 4);
  P.actme = (__hip_bfloat16*)carve((size_t)NT * NB * 320 * 2);
  P.obsmp = (__hip_bfloat16*)carve((size_t)NB * 1280 * 2);
  P.sprev = (__hip_bfloat16*)carve((size_t)NB * SD * 2);
  P.bel = (__hip_bfloat16*)carve((size_t)NB * BD * 2);
  P.hid = (__hip_bfloat16*)carve((size_t)NB * BD * 2);
  P.hpb = (__hip_bfloat16*)carve((size_t)NB * HD * 2);
  P.hqb = (__hip_bfloat16*)carve((size_t)NB * HD * 2);
  P.gi = (float*)carve((size_t)NB * 3 * BD * 4);
  P.gh = (float*)carve((size_t)NB * 3 * BD * 4);

  hipMemsetAsync(P.cnt, 0, cnt_bytes, stream);
  prep<<<1024, 256, 0, stream>>>(P);
  mega<<<NBLK, 256, 0, stream>>>(P);
}

// Round 7
// 5712.930 us; speedup vs baseline: 8.7642x; 1.1750x over previous
//
#include <hip/hip_runtime.h>
#include <hip/hip_bf16.h>

#define NT 50
#define NB 512
#define SD 256
#define BD 1024
#define HD 1024
#define ED 1024
#define MD 256
#define NBLK 512
#define GSZ (NBLK * 256)
#define PGSZ (1024 * 256)
#define K1BIG 0x40000000
#define NSLOT 256

typedef __attribute__((ext_vector_type(8))) short bf16x8;
typedef __attribute__((ext_vector_type(4))) float f32x4;

__device__ __forceinline__ void gload_lds16(const void* g, void* l) {
  __builtin_amdgcn_global_load_lds(
      (const __attribute__((address_space(1))) void*)g,
      (__attribute__((address_space(3))) void*)l, 16, 0, 0);
}

// ---- coherent access: async issue (NO wait) + explicit counted waits ----
__device__ __forceinline__ void cload16_async(const void* a, f32x4* r) {
  asm volatile("global_load_dwordx4 %0, %1, off sc0 sc1" : "=&v"(*r) : "v"(a) : "memory");
}
__device__ __forceinline__ void cload4_async(const void* a, float* r) {
  asm volatile("global_load_dword %0, %1, off sc0 sc1" : "=&v"(*r) : "v"(a) : "memory");
}
#define VMWAIT(N)                                        \
  asm volatile("s_waitcnt vmcnt(" #N ")" ::: "memory");  \
  __builtin_amdgcn_sched_barrier(0);

__device__ __forceinline__ void cstore16(void* g, f32x4 v) {
  asm volatile("global_store_dwordx4 %0, %1, off sc0 sc1" :: "v"(g), "v"(v) : "memory");
}
__device__ __forceinline__ void cstore4(void* g, float v) {
  asm volatile("global_store_dword %0, %1, off sc0 sc1" :: "v"(g), "v"(v) : "memory");
}
__device__ __forceinline__ void cstore2(void* g, unsigned v) {
  asm volatile("global_store_short %0, %1, off sc0 sc1" :: "v"(g), "v"(v) : "memory");
}
// non-temporal stores for write-once outputs (don't pollute L2)
__device__ __forceinline__ void ntstore16(void* g, f32x4 v) {
  asm volatile("global_store_dwordx4 %0, %1, off nt" :: "v"(g), "v"(v) : "memory");
}
__device__ __forceinline__ void ntstore4(void* g, float v) {
  asm volatile("global_store_dword %0, %1, off nt" :: "v"(g), "v"(v) : "memory");
}

__device__ __forceinline__ float sigmoidf_(float x) { return 1.0f / (1.0f + __expf(-x)); }
__device__ __forceinline__ float softplusf_(float x) {
  return (x > 0.0f) ? (x + log1pf(__expf(-x))) : log1pf(__expf(x));
}
__device__ __forceinline__ unsigned short bfb(float x) {
  __hip_bfloat16 h = __float2bfloat16(x);
  return __builtin_bit_cast(unsigned short, h);
}

// ---- fence-free hierarchical grid barrier (relaxed atomics only) ----
__device__ __forceinline__ void gbar(unsigned* cnt, int slot, int b) {
  asm volatile("s_waitcnt vmcnt(0) lgkmcnt(0)" ::: "memory");
  __syncthreads();
  if (threadIdx.x == 0) {
    unsigned* lc = cnt + slot * 128 + (b & 7) * 16;
    unsigned* gc = cnt + NSLOT * 128 + slot * 16;
    unsigned* fl = cnt + NSLOT * 144 + slot * 16;
    unsigned old = __hip_atomic_fetch_add(lc, 1u, __ATOMIC_RELAXED, __HIP_MEMORY_SCOPE_AGENT);
    if (old == (NBLK / 8 - 1)) {
      unsigned g = __hip_atomic_fetch_add(gc, 1u, __ATOMIC_RELAXED, __HIP_MEMORY_SCOPE_AGENT);
      if (g == 7u)
        __hip_atomic_store(fl, 1u, __ATOMIC_RELAXED, __HIP_MEMORY_SCOPE_AGENT);
    }
    while (__hip_atomic_load(fl, __ATOMIC_RELAXED, __HIP_MEMORY_SCOPE_AGENT) == 0u)
      __builtin_amdgcn_s_sleep(2);
  }
  __syncthreads();
}

// ---- 64x64 GEMM tile, BK=64, dbuf LDS, PIPELINED coherent A-staging ----
// A via async sc0sc1 loads (issue early / ds_write late, counted vmcnt);
// W via global_load_lds (plain-cached, L2-resident).
// EPI: 0 fp32(+bias) coherent; 1 relu->bf16(+bias) coherent;
//      3 relu->bf16(+bias+Cadd addend, coherent-read) coherent.
__device__ __noinline__ void gemm64(
    int EPI, char* lds,
    const __hip_bfloat16* __restrict__ A1, int lda1,
    const __hip_bfloat16* __restrict__ A2, int lda2, int K1,
    const __hip_bfloat16* __restrict__ Wr, int ldw, int nIter,
    const float* __restrict__ bias, const float* __restrict__ Cadd,
    float* __restrict__ Cf, __hip_bfloat16* __restrict__ Cb, int ldc, int m0) {
  const int tid = threadIdx.x;
  const int lane = tid & 63, w = tid >> 6;
  const int wr = w >> 1, wc = w & 1;
  f32x4 acc[2][2] = {};
  const __hip_bfloat16* a1r = A1 + (size_t)(m0 + lane) * lda1;
  const __hip_bfloat16* a2r = A2 ? (A2 + (size_t)(m0 + lane) * lda2) : a1r;
  const __hip_bfloat16* wrow = Wr + (size_t)lane * ldw;

  f32x4 rA0, rA1;
  auto issueA = [&](int it) {
    const int k0 = it << 6;
    const __hip_bfloat16* as = (k0 < K1) ? (a1r + k0) : (a2r + (k0 - K1));
    cload16_async(as + (2 * w) * 8, &rA0);
    cload16_async(as + (2 * w + 1) * 8, &rA1);
  };
  auto writeA = [&](int it) {
    char* la = lds + ((it & 1) << 14);
    *(f32x4*)(la + (2 * w) * 1024 + lane * 16) = rA0;
    *(f32x4*)(la + (2 * w + 1) * 1024 + lane * 16) = rA1;
  };
  auto stageW = [&](int it) {
    const int k0 = it << 6;
    char* lb = lds + ((it & 1) << 14) + 8192;
    gload_lds16(wrow + k0 + (2 * w) * 8, lb + (2 * w) * 1024);
    gload_lds16(wrow + k0 + (2 * w + 1) * 8, lb + (2 * w + 1) * 1024);
  };

  issueA(0);
  VMWAIT(0)
  writeA(0);
  stageW(0);

  const int kq = lane >> 4, r15 = lane & 15;
  for (int i = 0; i < nIter; ++i) {
    __syncthreads();  // drains vmcnt (W(i)) + lgkm (ds_write) for all waves
    if (i + 1 < nIter) {
      issueA(i + 1);
      stageW(i + 1);
    }
    const char* la = lds + ((i & 1) << 14);
    const char* lb = la + 8192;
#pragma unroll
    for (int s = 0; s < 2; ++s) {
      bf16x8 af[2], bfr[2];
#pragma unroll
      for (int m = 0; m < 2; ++m)
        af[m] = *(const bf16x8*)(la + (size_t)((s * 4 + kq) * 64 + wr * 32 + m * 16 + r15) * 16);
#pragma unroll
      for (int n = 0; n < 2; ++n)
        bfr[n] = *(const bf16x8*)(lb + (size_t)((s * 4 + kq) * 64 + wc * 32 + n * 16 + r15) * 16);
#pragma unroll
      for (int m = 0; m < 2; ++m)
#pragma unroll
        for (int n = 0; n < 2; ++n)
          acc[m][n] = __builtin_amdgcn_mfma_f32_16x16x32_bf16(af[m], bfr[n], acc[m][n], 0, 0, 0);
    }
    if (i + 1 < nIter) {
      VMWAIT(2)  // drains A(i+1) (oldest); W(i+1) may stay in flight
      writeA(i + 1);
    }
  }

  const int rg = lane >> 4;
  float ad[2][2][4];
  if (EPI == 3) {
#pragma unroll
    for (int m = 0; m < 2; ++m)
#pragma unroll
      for (int n = 0; n < 2; ++n) {
        const int col = wc * 32 + n * 16 + r15;
#pragma unroll
        for (int i2 = 0; i2 < 4; ++i2) {
          const int row = m0 + wr * 32 + m * 16 + rg * 4 + i2;
          cload4_async(Cadd + (size_t)row * ldc + col, &ad[m][n][i2]);
        }
      }
    VMWAIT(0)
  }
#pragma unroll
  for (int m = 0; m < 2; ++m) {
#pragma unroll
    for (int n = 0; n < 2; ++n) {
      const int col = wc * 32 + n * 16 + r15;
      const float bv = bias ? bias[col] : 0.0f;
#pragma unroll
      for (int i2 = 0; i2 < 4; ++i2) {
        const int row = m0 + wr * 32 + m * 16 + rg * 4 + i2;
        float v = acc[m][n][i2] + bv;
        if (EPI == 3) v += ad[m][n][i2];
        if (EPI != 0) {
          v = v > 0.0f ? v : 0.0f;
          cstore2(Cb + (size_t)row * ldc + col, (unsigned)bfb(v));
        } else {
          cstore4(Cf + (size_t)row * ldc + col, v);
        }
      }
    }
  }
}

// ---- head GEMM (K=1024) with fused prior/posterior epilogue; W pre-interleaved ----
__device__ __noinline__ void gemm_head64(
    char* lds, const __hip_bfloat16* __restrict__ A,
    const __hip_bfloat16* __restrict__ Wr, const float* __restrict__ bias,
    const float* __restrict__ noise, float* __restrict__ st_o, float* __restrict__ mn_o,
    float* __restrict__ sd_o, const float* __restrict__ ntn,
    __hip_bfloat16* __restrict__ sprev, int isq, int n0, int m0) {
  const int tid = threadIdx.x;
  const int lane = tid & 63, w = tid >> 6;
  const int wr = w >> 1, wc = w & 1;
  f32x4 acc[2][2] = {};
  const __hip_bfloat16* ar = A + (size_t)(m0 + lane) * BD;
  const __hip_bfloat16* wrow = Wr + (size_t)lane * BD;

  f32x4 rA0, rA1;
  auto issueA = [&](int it) {
    const int k0 = it << 6;
    cload16_async(ar + k0 + (2 * w) * 8, &rA0);
    cload16_async(ar + k0 + (2 * w + 1) * 8, &rA1);
  };
  auto writeA = [&](int it) {
    char* la = lds + ((it & 1) << 14);
    *(f32x4*)(la + (2 * w) * 1024 + lane * 16) = rA0;
    *(f32x4*)(la + (2 * w + 1) * 1024 + lane * 16) = rA1;
  };
  auto stageW = [&](int it) {
    const int k0 = it << 6;
    char* lb = lds + ((it & 1) << 14) + 8192;
    gload_lds16(wrow + k0 + (2 * w) * 8, lb + (2 * w) * 1024);
    gload_lds16(wrow + k0 + (2 * w + 1) * 8, lb + (2 * w + 1) * 1024);
  };

  issueA(0);
  VMWAIT(0)
  writeA(0);
  stageW(0);

  const int kq = lane >> 4, r15 = lane & 15;
  for (int i = 0; i < 16; ++i) {
    __syncthreads();
    if (i + 1 < 16) {
      issueA(i + 1);
      stageW(i + 1);
    }
    const char* la = lds + ((i & 1) << 14);
    const char* lb = la + 8192;
#pragma unroll
    for (int s = 0; s < 2; ++s) {
      bf16x8 af[2], bfr[2];
#pragma unroll
      for (int m = 0; m < 2; ++m)
        af[m] = *(const bf16x8*)(la + (size_t)((s * 4 + kq) * 64 + wr * 32 + m * 16 + r15) * 16);
#pragma unroll
      for (int n = 0; n < 2; ++n)
        bfr[n] = *(const bf16x8*)(lb + (size_t)((s * 4 + kq) * 64 + wc * 32 + n * 16 + r15) * 16);
#pragma unroll
      for (int m = 0; m < 2; ++m)
#pragma unroll
        for (int n = 0; n < 2; ++n)
          acc[m][n] = __builtin_amdgcn_mfma_f32_16x16x32_bf16(af[m], bfr[n], acc[m][n], 0, 0, 0);
    }
    if (i + 1 < 16) {
      VMWAIT(2)
      writeA(i + 1);
    }
  }

  const int rg = lane >> 4;
  const bool even = (r15 & 1) == 0;
#pragma unroll
  for (int m = 0; m < 2; ++m) {
#pragma unroll
    for (int n = 0; n < 2; ++n) {
      const int col = n0 + wc * 32 + n * 16 + r15;  // 0..511 interleaved mean/raw
      const int j = col >> 1;
      const float bv = bias[col];
#pragma unroll
      for (int i2 = 0; i2 < 4; ++i2) {
        const int row = m0 + wr * 32 + m * 16 + rg * 4 + i2;
        float v = acc[m][n][i2] + bv;
        float partner = __shfl_xor(v, 1);
        float mean = even ? v : partner;
        float raw = even ? partner : v;
        float sd = fminf(softplusf_(raw) + 0.1f, 5.0f);
        const size_t o = (size_t)row * SD + j;
        if (even) {
          float st = mean + sd * noise[o];
          ntstore4(mn_o + o, mean);
          ntstore4(st_o + o, st);
          if (isq) cstore2(sprev + o, (unsigned)bfb(st * ntn[row]));
        } else {
          ntstore4(sd_o + o, sd);
        }
      }
    }
  }
}

struct Args {
  const float *prev_state, *actions, *prev_belief, *observations, *nonterminals,
      *me, *mp, *noise_p, *noise_q,
      *W_sa, *b_sa, *W_ih, *b_ih, *W_hh, *b_hh,
      *W_bp, *b_bp, *W_sp, *b_sp, *W_bq, *b_bq, *W_sq, *b_sq;
  float* out;
  unsigned* cnt;
  __hip_bfloat16 *Wsa, *Wih, *Whh, *Wbp, *Wbq, *Wsp, *Wsq;
  __hip_bfloat16 *actme, *obsmp, *sprev, *bel, *hid, *hpb, *hqb;
  float *gi, *gh, *hq_obs;
  float *bsp_ro, *bsq_ro;
};

// ---------------- prep ----------------
__global__ __launch_bounds__(256) void prep(Args P) {
  const int gtid = blockIdx.x * 256 + threadIdx.x;
  for (int i = gtid; i < BD * 576; i += PGSZ) {  // W_sa padded K 544->576
    int r = i / 576, k = i - r * 576;
    P.Wsa[i] = __float2bfloat16(k < 544 ? P.W_sa[(size_t)r * 544 + k] : 0.0f);
  }
  for (int i = gtid; i < 3 * BD * BD; i += PGSZ) P.Wih[i] = __float2bfloat16(P.W_ih[i]);
  for (int i = gtid; i < 3 * BD * BD; i += PGSZ) P.Whh[i] = __float2bfloat16(P.W_hh[i]);
  for (int i = gtid; i < HD * BD; i += PGSZ) P.Wbp[i] = __float2bfloat16(P.W_bp[i]);
  for (int i = gtid; i < HD * 2304; i += PGSZ) P.Wbq[i] = __float2bfloat16(P.W_bq[i]);
  for (int i = gtid; i < 512 * HD; i += PGSZ) {  // head W interleave
    int r = i >> 10, k = i & 1023;
    int dr = (r < 256) ? (2 * r) : (2 * (r - 256) + 1);
    P.Wsp[(size_t)dr * 1024 + k] = __float2bfloat16(P.W_sp[i]);
    P.Wsq[(size_t)dr * 1024 + k] = __float2bfloat16(P.W_sq[i]);
  }
  for (int i = gtid; i < 512; i += PGSZ) {
    int dr = (i < 256) ? (2 * i) : (2 * (i - 256) + 1);
    P.bsp_ro[dr] = P.b_sp[i];
    P.bsq_ro[dr] = P.b_sq[i];
  }
  for (int i = gtid; i < NT * NB * 320; i += PGSZ) {  // [act(32)|me(256)|pad(32)]
    int tb = i / 320, j = i - tb * 320;
    float v = (j < 32) ? P.actions[(size_t)tb * 32 + j]
                       : (j < 288 ? P.me[(size_t)tb * 256 + (j - 32)] : 0.0f);
    P.actme[i] = __float2bfloat16(v);
  }
  for (int i = gtid; i < NB * 1280; i += PGSZ) {  // obsmp(0)
    int bb = i / 1280, j = i - bb * 1280;
    float v = (j < ED) ? P.observations[(size_t)bb * ED + j] : P.mp[(size_t)bb * MD + (j - ED)];
    P.obsmp[i] = __float2bfloat16(v);
  }
  for (int i = gtid; i < NB * SD; i += PGSZ) {
    int r = i >> 8;
    P.sprev[i] = __float2bfloat16(P.prev_state[i] * P.nonterminals[r]);
  }
  for (int i = gtid; i < NB * BD; i += PGSZ) P.bel[i] = __float2bfloat16(P.prev_belief[i]);
}

// ---------------- mega: all 50 steps, grid-resident, fence-free ----------------
__global__ __launch_bounds__(256, 4) void mega(Args P) {
  __shared__ alignas(16) char lds[32768];
  const int b = blockIdx.x, tid = threadIdx.x;
  const int gtid = b * 256 + tid;

  const size_t o_ps = (size_t)NT * NB * BD;
  const size_t blk = (size_t)NT * NB * SD;

  for (int t = 0; t < NT; ++t) {
    const int s0 = t * 5;
    // ---- A: hid (blocks 0-127, 9 it) ; gh (blocks 128-511, 16 it) ----
    if (b < 128) {
      const int u = (b & 7) * 16 + (b >> 3), n = u >> 3, m = u & 7;
      gemm64(1, lds, P.sprev, SD, P.actme + (size_t)t * NB * 320, 320, 256,
             P.Wsa + (size_t)n * 64 * 576, 576, 9,
             P.b_sa + n * 64, nullptr, nullptr, P.hid + n * 64, BD, m * 64);
    } else {
      const int b2 = b - 128;
      const int u = (b2 & 7) * 48 + (b2 >> 3), n = u >> 3, m = u & 7;
      gemm64(0, lds, P.bel, BD, nullptr, 0, K1BIG,
             P.Whh + (size_t)n * 64 * BD, BD, 16,
             P.b_hh + n * 64, nullptr, P.gh + n * 64, nullptr, 3 * BD, m * 64);
    }
    gbar(P.cnt, s0 + 0, b);
    // ---- B: gi (blocks 0-383, 16 it) ; t=0: obs-partial(0) (blocks 384-511, 20 it) ----
    if (b < 384) {
      const int u = (b & 7) * 48 + (b >> 3), n = u >> 3, m = u & 7;
      gemm64(0, lds, P.hid, BD, nullptr, 0, K1BIG,
             P.Wih + (size_t)n * 64 * BD, BD, 16,
             P.b_ih + n * 64, nullptr, P.gi + n * 64, nullptr, 3 * BD, m * 64);
    } else if (t == 0) {
      const int b2 = b - 384;
      const int u = (b2 & 7) * 16 + (b2 >> 3), n = u >> 3, m = u & 7;
      gemm64(0, lds, P.obsmp, 1280, nullptr, 0, K1BIG,
             P.Wbq + (size_t)n * 64 * 2304 + 1024, 2304, 20,
             nullptr, nullptr, P.hq_obs + n * 64, nullptr, 1024, m * 64);
    }
    gbar(P.cnt, s0 + 1, b);
    // ---- C: GRU pointwise (gtid<65536) + obsmp(t+1) pack ----
    if (gtid < 65536) {
      const int bb = gtid >> 7, j0 = (gtid & 127) << 3;
      const float* gib = P.gi + (size_t)bb * 3072 + j0;
      const float* ghb = P.gh + (size_t)bb * 3072 + j0;
      f32x4 ir0, ir1, iz0, iz1, in0, in1, hr0, hr1, hz0, hz1, hn0, hn1, hbv;
      cload16_async(gib, &ir0);
      cload16_async(gib + 4, &ir1);
      cload16_async(gib + 1024, &iz0);
      cload16_async(gib + 1028, &iz1);
      cload16_async(gib + 2048, &in0);
      cload16_async(gib + 2052, &in1);
      cload16_async(ghb, &hr0);
      cload16_async(ghb + 4, &hr1);
      cload16_async(ghb + 1024, &hz0);
      cload16_async(ghb + 1028, &hz1);
      cload16_async(ghb + 2048, &hn0);
      cload16_async(ghb + 2052, &hn1);
      cload16_async(P.bel + (size_t)bb * BD + j0, &hbv);
      VMWAIT(0)
      bf16x8 hb = __builtin_bit_cast(bf16x8, hbv);
      float o[8];
      unsigned short nb[8];
#pragma unroll
      for (int k = 0; k < 8; ++k) {
        float gr = (k < 4 ? ir0[k] : ir1[k - 4]) + (k < 4 ? hr0[k] : hr1[k - 4]);
        float gz = (k < 4 ? iz0[k] : iz1[k - 4]) + (k < 4 ? hz0[k] : hz1[k - 4]);
        float hn = (k < 4 ? hn0[k] : hn1[k - 4]);
        float in_ = (k < 4 ? in0[k] : in1[k - 4]);
        float r_ = sigmoidf_(gr);
        float z_ = sigmoidf_(gz);
        float n_ = tanhf(in_ + r_ * hn);
        __hip_bfloat16 hv16 = __builtin_bit_cast(__hip_bfloat16, (unsigned short)hb[k]);
        float hv = __bfloat162float(hv16);
        float bel = (1.0f - z_) * n_ + z_ * hv;
        o[k] = bel;
        nb[k] = bfb(bel);
      }
      float* ob = P.out + (size_t)t * NB * BD + (size_t)bb * BD + j0;
      ntstore16(ob, f32x4{o[0], o[1], o[2], o[3]});
      ntstore16(ob + 4, f32x4{o[4], o[5], o[6], o[7]});
      cstore16(P.bel + (size_t)bb * BD + j0, __builtin_bit_cast(f32x4, *(bf16x8*)nb));
    } else if (gtid < 65536 + 40960 && t + 1 < NT) {
      const int k = gtid - 65536;
      const int bb = k / 80, rr = k - bb * 80, j0 = rr << 4;  // 16 elems/thread
      const float* src = (j0 < ED)
          ? (P.observations + (size_t)(t + 1) * NB * ED + (size_t)bb * ED + j0)
          : (P.mp + (size_t)(t + 1) * NB * MD + (size_t)bb * MD + (j0 - ED));
      unsigned short nb[16];
#pragma unroll
      for (int q = 0; q < 4; ++q) {
        f32x4 v = *(const f32x4*)(src + q * 4);
#pragma unroll
        for (int kk = 0; kk < 4; ++kk) nb[q * 4 + kk] = bfb(v[kk]);
      }
      cstore16(P.obsmp + (size_t)bb * 1280 + j0, __builtin_bit_cast(f32x4, *(bf16x8*)nb));
      cstore16(P.obsmp + (size_t)bb * 1280 + j0 + 8, __builtin_bit_cast(f32x4, *(bf16x8*)(nb + 8)));
    }
    gbar(P.cnt, s0 + 2, b);
    // ---- D: hp (0-127, 16 it) ; hq-final = bel@Wbq[:, :1024] + hq_obs (128-255, 16 it) ----
    if (b < 128) {
      const int u = (b & 7) * 16 + (b >> 3), n = u >> 3, m = u & 7;
      gemm64(1, lds, P.bel, BD, nullptr, 0, K1BIG,
             P.Wbp + (size_t)n * 64 * BD, BD, 16,
             P.b_bp + n * 64, nullptr, nullptr, P.hpb + n * 64, HD, m * 64);
    } else if (b < 256) {
      const int b2 = b - 128;
      const int u = (b2 & 7) * 16 + (b2 >> 3), n = u >> 3, m = u & 7;
      gemm64(3, lds, P.bel, BD, nullptr, 0, K1BIG,
             P.Wbq + (size_t)n * 64 * 2304, 2304, 16,
             P.b_bq + n * 64, P.hq_obs + n * 64, nullptr, P.hqb + n * 64, HD, m * 64);
    }
    gbar(P.cnt, s0 + 3, b);
    // ---- E: heads (0-127, 16 it) ; obs-partial(t+1) (128-255, 20 it) ----
    if (b < 128) {
      const int u = (b & 7) * 16 + (b >> 3);
      const int pq = u >> 6, rr = u & 63, n = rr >> 3, m = rr & 7;
      const float* ntn = P.nonterminals + (size_t)((t + 1 < NT) ? t + 1 : t) * NB;
      const size_t to = (size_t)t * NB * SD;
      if (pq == 0)
        gemm_head64(lds, P.hpb, P.Wsp + (size_t)n * 64 * BD, P.bsp_ro,
                    P.noise_p + to, P.out + o_ps + to, P.out + o_ps + blk + to,
                    P.out + o_ps + 2 * blk + to, ntn, P.sprev, 0, n * 64, m * 64);
      else
        gemm_head64(lds, P.hqb, P.Wsq + (size_t)n * 64 * BD, P.bsq_ro,
                    P.noise_q + to, P.out + o_ps + 3 * blk + to, P.out + o_ps + 4 * blk + to,
                    P.out + o_ps + 5 * blk + to, ntn, P.sprev, 1, n * 64, m * 64);
    } else if (b < 256 && t + 1 < NT) {
      const int b2 = b - 128;
      const int u = (b2 & 7) * 16 + (b2 >> 3), n = u >> 3, m = u & 7;
      gemm64(0, lds, P.obsmp, 1280, nullptr, 0, K1BIG,
             P.Wbq + (size_t)n * 64 * 2304 + 1024, 2304, 20,
             nullptr, nullptr, P.hq_obs + n * 64, nullptr, 1024, m * 64);
    }
    gbar(P.cnt, s0 + 4, b);
  }
}

// ---------------- host ----------------

extern "C" void kernel_launch(void* const* d_in, const int* in_sizes, int n_in,
                              void* d_out, int out_size, void* d_ws, size_t ws_size,
                              hipStream_t stream) {
  Args P;
  P.prev_state = (const float*)d_in[0];
  P.actions = (const float*)d_in[1];
  P.prev_belief = (const float*)d_in[2];
  P.observations = (const float*)d_in[3];
  P.nonterminals = (const float*)d_in[4];
  P.me = (const float*)d_in[5];
  P.mp = (const float*)d_in[6];
  P.noise_p = (const float*)d_in[7];
  P.noise_q = (const float*)d_in[8];
  P.W_sa = (const float*)d_in[9];  P.b_sa = (const float*)d_in[10];
  P.W_ih = (const float*)d_in[11]; P.b_ih = (const float*)d_in[12];
  P.W_hh = (const float*)d_in[13]; P.b_hh = (const float*)d_in[14];
  P.W_bp = (const float*)d_in[15]; P.b_bp = (const float*)d_in[16];
  P.W_sp = (const float*)d_in[17]; P.b_sp = (const float*)d_in[18];
  P.W_bq = (const float*)d_in[19]; P.b_bq = (const float*)d_in[20];
  P.W_sq = (const float*)d_in[21]; P.b_sq = (const float*)d_in[22];
  P.out = (float*)d_out;

  char* p = (char*)d_ws;
  auto carve = [&](size_t bytes) -> char* {
    char* r = p;
    p += (bytes + 255) & ~(size_t)255;
    return r;
  };
  const size_t cnt_bytes = (size_t)NSLOT * 160 * 4;
  P.cnt = (unsigned*)carve(cnt_bytes);
  P.Wsa = (__hip_bfloat16*)carve((size_t)BD * 576 * 2);
  P.Wih = (__hip_bfloat16*)carve((size_t)3 * BD * BD * 2);
  P.Whh = (__hip_bfloat16*)carve((size_t)3 * BD * BD * 2);
  P.Wbp = (__hip_bfloat16*)carve((size_t)HD * BD * 2);
  P.Wbq = (__hip_bfloat16*)carve((size_t)HD * 2304 * 2);
  P.Wsp = (__hip_bfloat16*)carve((size_t)512 * HD * 2);
  P.Wsq = (__hip_bfloat16*)carve((size_t)512 * HD * 2);
  P.bsp_ro = (float*)carve(512 * 4);
  P.bsq_ro = (float*)carve(512 * 4);
  P.actme = (__hip_bfloat16*)carve((size_t)NT * NB * 320 * 2);
  P.obsmp = (__hip_bfloat16*)carve((size_t)NB * 1280 * 2);
  P.sprev = (__hip_bfloat16*)carve((size_t)NB * SD * 2);
  P.bel = (__hip_bfloat16*)carve((size_t)NB * BD * 2);
  P.hid = (__hip_bfloat16*)carve((size_t)NB * BD * 2);
  P.hpb = (__hip_bfloat16*)carve((size_t)NB * HD * 2);
  P.hqb = (__hip_bfloat16*)carve((size_t)NB * HD * 2);
  P.gi = (float*)carve((size_t)NB * 3 * BD * 4);
  P.gh = (float*)carve((size_t)NB * 3 * BD * 4);
  P.hq_obs = (float*)carve((size_t)NB * HD * 4);

  hipMemsetAsync(P.cnt, 0, cnt_bytes, stream);
  prep<<<1024, 256, 0, stream>>>(P);
  mega<<<NBLK, 256, 0, stream>>>(P);
}

// Round 8
// 5487.806 us; speedup vs baseline: 9.1237x; 1.0410x over previous
//
#include <hip/hip_runtime.h>
#include <hip/hip_bf16.h>

#define NT 50
#define NB 512
#define SD 256
#define BD 1024
#define HD 1024
#define ED 1024
#define MD 256
#define NBLK 512
#define PGSZ (1024 * 256)
#define K1BIG 0x40000000

typedef __attribute__((ext_vector_type(8))) short bf16x8;
typedef __attribute__((ext_vector_type(4))) float f32x4;

__device__ __forceinline__ void gload_lds16(const void* g, void* l) {
  __builtin_amdgcn_global_load_lds(
      (const __attribute__((address_space(1))) void*)g,
      (__attribute__((address_space(3))) void*)l, 16, 0, 0);
}

// ---- XCD-local (sc0: bypass L1, hit local L2) activation access ----
__device__ __forceinline__ void aload16(const void* a, f32x4* r) {
  asm volatile("global_load_dwordx4 %0, %1, off sc0" : "=&v"(*r) : "v"(a) : "memory");
}
__device__ __forceinline__ void aload4(const void* a, float* r) {
  asm volatile("global_load_dword %0, %1, off sc0" : "=&v"(*r) : "v"(a) : "memory");
}
#define VMWAIT(N)                                        \
  asm volatile("s_waitcnt vmcnt(" #N ")" ::: "memory");  \
  __builtin_amdgcn_sched_barrier(0);

__device__ __forceinline__ void astore16(void* g, f32x4 v) {
  asm volatile("global_store_dwordx4 %0, %1, off sc0" :: "v"(g), "v"(v) : "memory");
}
__device__ __forceinline__ void astore4(void* g, float v) {
  asm volatile("global_store_dword %0, %1, off sc0" :: "v"(g), "v"(v) : "memory");
}
__device__ __forceinline__ void astore2(void* g, unsigned v) {
  asm volatile("global_store_short %0, %1, off sc0" :: "v"(g), "v"(v) : "memory");
}
// non-temporal stores for write-once outputs
__device__ __forceinline__ void ntstore16(void* g, f32x4 v) {
  asm volatile("global_store_dwordx4 %0, %1, off nt" :: "v"(g), "v"(v) : "memory");
}
__device__ __forceinline__ void ntstore4(void* g, float v) {
  asm volatile("global_store_dword %0, %1, off nt" :: "v"(g), "v"(v) : "memory");
}

__device__ __forceinline__ float sigmoidf_(float x) { return 1.0f / (1.0f + __expf(-x)); }
__device__ __forceinline__ float softplusf_(float x) {
  return (x > 0.0f) ? (x + log1pf(__expf(-x))) : log1pf(__expf(x));
}
__device__ __forceinline__ unsigned short bfb(float x) {
  __hip_bfloat16 h = __float2bfloat16(x);
  return __builtin_bit_cast(unsigned short, h);
}

// ---- per-XCD barrier: count nx arrivals at a per-(instance,xcd) line ----
__device__ __forceinline__ void xbar(unsigned* cnt, int inst, int xcd, int nx) {
  asm volatile("s_waitcnt vmcnt(0) lgkmcnt(0)" ::: "memory");
  __syncthreads();
  if (threadIdx.x == 0) {
    unsigned* c = cnt + 256 + (size_t)(inst * 8 + xcd) * 16;
    __hip_atomic_fetch_add(c, 1u, __ATOMIC_RELAXED, __HIP_MEMORY_SCOPE_AGENT);
    while (__hip_atomic_load(c, __ATOMIC_RELAXED, __HIP_MEMORY_SCOPE_AGENT) < (unsigned)nx)
      __builtin_amdgcn_s_sleep(4);
  }
  __syncthreads();
}

// ---- 64x64 GEMM tile, BK=64, dbuf LDS, pipelined XCD-local A staging ----
// A via sc0 async loads (issue early / ds_write late, counted vmcnt);
// W via global_load_lds (plain; L2/L3-cached read-only).
// EPI: 0 fp32(+bias) sc0 out; 1 relu->bf16(+bias) sc0 out;
//      3 relu->bf16(+bias+Cadd sc0 addend) sc0 out.
__device__ __noinline__ void gemm64(
    int EPI, char* lds,
    const __hip_bfloat16* __restrict__ A1, int lda1,
    const __hip_bfloat16* __restrict__ A2, int lda2, int K1,
    const __hip_bfloat16* __restrict__ Wr, int ldw, int nIter,
    const float* __restrict__ bias, const float* __restrict__ Cadd,
    float* __restrict__ Cf, __hip_bfloat16* __restrict__ Cb, int ldc, int m0) {
  const int tid = threadIdx.x;
  const int lane = tid & 63, w = tid >> 6;
  const int wr = w >> 1, wc = w & 1;
  f32x4 acc[2][2] = {};
  const __hip_bfloat16* a1r = A1 + (size_t)(m0 + lane) * lda1;
  const __hip_bfloat16* a2r = A2 ? (A2 + (size_t)(m0 + lane) * lda2) : a1r;
  const __hip_bfloat16* wrow = Wr + (size_t)lane * ldw;

  f32x4 rA0, rA1;
  auto issueA = [&](int it) {
    const int k0 = it << 6;
    const __hip_bfloat16* as = (k0 < K1) ? (a1r + k0) : (a2r + (k0 - K1));
    aload16(as + (2 * w) * 8, &rA0);
    aload16(as + (2 * w + 1) * 8, &rA1);
  };
  auto writeA = [&](int it) {
    char* la = lds + ((it & 1) << 14);
    *(f32x4*)(la + (2 * w) * 1024 + lane * 16) = rA0;
    *(f32x4*)(la + (2 * w + 1) * 1024 + lane * 16) = rA1;
  };
  auto stageW = [&](int it) {
    const int k0 = it << 6;
    char* lb = lds + ((it & 1) << 14) + 8192;
    gload_lds16(wrow + k0 + (2 * w) * 8, lb + (2 * w) * 1024);
    gload_lds16(wrow + k0 + (2 * w + 1) * 8, lb + (2 * w + 1) * 1024);
  };

  __syncthreads();  // guard LDS reuse across back-to-back calls
  issueA(0);
  VMWAIT(0)
  writeA(0);
  stageW(0);

  const int kq = lane >> 4, r15 = lane & 15;
  for (int i = 0; i < nIter; ++i) {
    __syncthreads();
    if (i + 1 < nIter) {
      issueA(i + 1);
      stageW(i + 1);
    }
    const char* la = lds + ((i & 1) << 14);
    const char* lb = la + 8192;
#pragma unroll
    for (int s = 0; s < 2; ++s) {
      bf16x8 af[2], bfr[2];
#pragma unroll
      for (int m = 0; m < 2; ++m)
        af[m] = *(const bf16x8*)(la + (size_t)((s * 4 + kq) * 64 + wr * 32 + m * 16 + r15) * 16);
#pragma unroll
      for (int n = 0; n < 2; ++n)
        bfr[n] = *(const bf16x8*)(lb + (size_t)((s * 4 + kq) * 64 + wc * 32 + n * 16 + r15) * 16);
#pragma unroll
      for (int m = 0; m < 2; ++m)
#pragma unroll
        for (int n = 0; n < 2; ++n)
          acc[m][n] = __builtin_amdgcn_mfma_f32_16x16x32_bf16(af[m], bfr[n], acc[m][n], 0, 0, 0);
    }
    if (i + 1 < nIter) {
      VMWAIT(2)  // A(i+1) done; W(i+1) may stay in flight
      writeA(i + 1);
    }
  }

  const int rg = lane >> 4;
  float ad[2][2][4];
  if (EPI == 3) {
#pragma unroll
    for (int m = 0; m < 2; ++m)
#pragma unroll
      for (int n = 0; n < 2; ++n) {
        const int col = wc * 32 + n * 16 + r15;
#pragma unroll
        for (int i2 = 0; i2 < 4; ++i2) {
          const int row = m0 + wr * 32 + m * 16 + rg * 4 + i2;
          aload4(Cadd + (size_t)row * ldc + col, &ad[m][n][i2]);
        }
      }
    VMWAIT(0)
  }
#pragma unroll
  for (int m = 0; m < 2; ++m) {
#pragma unroll
    for (int n = 0; n < 2; ++n) {
      const int col = wc * 32 + n * 16 + r15;
      const float bv = bias ? bias[col] : 0.0f;
#pragma unroll
      for (int i2 = 0; i2 < 4; ++i2) {
        const int row = m0 + wr * 32 + m * 16 + rg * 4 + i2;
        float v = acc[m][n][i2] + bv;
        if (EPI == 3) v += ad[m][n][i2];
        if (EPI != 0) {
          v = v > 0.0f ? v : 0.0f;
          astore2(Cb + (size_t)row * ldc + col, (unsigned)bfb(v));
        } else {
          astore4(Cf + (size_t)row * ldc + col, v);
        }
      }
    }
  }
}

// ---- head GEMM (K=1024) with fused prior/posterior epilogue; W pre-interleaved ----
__device__ __noinline__ void gemm_head64(
    char* lds, const __hip_bfloat16* __restrict__ A,
    const __hip_bfloat16* __restrict__ Wr, const float* __restrict__ bias,
    const float* __restrict__ noise, float* __restrict__ st_o, float* __restrict__ mn_o,
    float* __restrict__ sd_o, const float* __restrict__ ntn,
    __hip_bfloat16* __restrict__ sprev, int isq, int n0, int m0) {
  const int tid = threadIdx.x;
  const int lane = tid & 63, w = tid >> 6;
  const int wr = w >> 1, wc = w & 1;
  f32x4 acc[2][2] = {};
  const __hip_bfloat16* ar = A + (size_t)(m0 + lane) * BD;
  const __hip_bfloat16* wrow = Wr + (size_t)lane * BD;

  f32x4 rA0, rA1;
  auto issueA = [&](int it) {
    const int k0 = it << 6;
    aload16(ar + k0 + (2 * w) * 8, &rA0);
    aload16(ar + k0 + (2 * w + 1) * 8, &rA1);
  };
  auto writeA = [&](int it) {
    char* la = lds + ((it & 1) << 14);
    *(f32x4*)(la + (2 * w) * 1024 + lane * 16) = rA0;
    *(f32x4*)(la + (2 * w + 1) * 1024 + lane * 16) = rA1;
  };
  auto stageW = [&](int it) {
    const int k0 = it << 6;
    char* lb = lds + ((it & 1) << 14) + 8192;
    gload_lds16(wrow + k0 + (2 * w) * 8, lb + (2 * w) * 1024);
    gload_lds16(wrow + k0 + (2 * w + 1) * 8, lb + (2 * w + 1) * 1024);
  };

  __syncthreads();
  issueA(0);
  VMWAIT(0)
  writeA(0);
  stageW(0);

  const int kq = lane >> 4, r15 = lane & 15;
  for (int i = 0; i < 16; ++i) {
    __syncthreads();
    if (i + 1 < 16) {
      issueA(i + 1);
      stageW(i + 1);
    }
    const char* la = lds + ((i & 1) << 14);
    const char* lb = la + 8192;
#pragma unroll
    for (int s = 0; s < 2; ++s) {
      bf16x8 af[2], bfr[2];
#pragma unroll
      for (int m = 0; m < 2; ++m)
        af[m] = *(const bf16x8*)(la + (size_t)((s * 4 + kq) * 64 + wr * 32 + m * 16 + r15) * 16);
#pragma unroll
      for (int n = 0; n < 2; ++n)
        bfr[n] = *(const bf16x8*)(lb + (size_t)((s * 4 + kq) * 64 + wc * 32 + n * 16 + r15) * 16);
#pragma unroll
      for (int m = 0; m < 2; ++m)
#pragma unroll
        for (int n = 0; n < 2; ++n)
          acc[m][n] = __builtin_amdgcn_mfma_f32_16x16x32_bf16(af[m], bfr[n], acc[m][n], 0, 0, 0);
    }
    if (i + 1 < 16) {
      VMWAIT(2)
      writeA(i + 1);
    }
  }

  const int rg = lane >> 4;
  const bool even = (r15 & 1) == 0;
#pragma unroll
  for (int m = 0; m < 2; ++m) {
#pragma unroll
    for (int n = 0; n < 2; ++n) {
      const int col = n0 + wc * 32 + n * 16 + r15;  // interleaved mean/raw, 0..511
      const int j = col >> 1;
      const float bv = bias[col];
#pragma unroll
      for (int i2 = 0; i2 < 4; ++i2) {
        const int row = m0 + wr * 32 + m * 16 + rg * 4 + i2;
        float v = acc[m][n][i2] + bv;
        float partner = __shfl_xor(v, 1);
        float mean = even ? v : partner;
        float raw = even ? partner : v;
        float sd = fminf(softplusf_(raw) + 0.1f, 5.0f);
        const size_t o = (size_t)row * SD + j;
        if (even) {
          float st = mean + sd * noise[o];
          ntstore4(mn_o + o, mean);
          ntstore4(st_o + o, st);
          if (isq) astore2(sprev + o, (unsigned)bfb(st * ntn[row]));
        } else {
          ntstore4(sd_o + o, sd);
        }
      }
    }
  }
}

struct Args {
  const float *prev_state, *actions, *prev_belief, *observations, *nonterminals,
      *me, *mp, *noise_p, *noise_q,
      *W_sa, *b_sa, *W_ih, *b_ih, *W_hh, *b_hh,
      *W_bp, *b_bp, *W_sp, *b_sp, *W_bq, *b_bq, *W_sq, *b_sq;
  float* out;
  unsigned* cnt;
  __hip_bfloat16 *Wsa, *Wih, *Whh, *Wbp, *Wbq, *Wsp, *Wsq;
  __hip_bfloat16 *actme, *obsmp, *sprev, *bel, *hid, *hpb, *hqb;
  float *gi, *gh, *hq_obs;
  float *bsp_ro, *bsq_ro;
};

// ---------------- prep ----------------
__global__ __launch_bounds__(256) void prep(Args P) {
  const int gtid = blockIdx.x * 256 + threadIdx.x;
  for (int i = gtid; i < BD * 576; i += PGSZ) {  // W_sa padded K 544->576
    int r = i / 576, k = i - r * 576;
    P.Wsa[i] = __float2bfloat16(k < 544 ? P.W_sa[(size_t)r * 544 + k] : 0.0f);
  }
  for (int i = gtid; i < 3 * BD * BD; i += PGSZ) P.Wih[i] = __float2bfloat16(P.W_ih[i]);
  for (int i = gtid; i < 3 * BD * BD; i += PGSZ) P.Whh[i] = __float2bfloat16(P.W_hh[i]);
  for (int i = gtid; i < HD * BD; i += PGSZ) P.Wbp[i] = __float2bfloat16(P.W_bp[i]);
  for (int i = gtid; i < HD * 2304; i += PGSZ) P.Wbq[i] = __float2bfloat16(P.W_bq[i]);
  for (int i = gtid; i < 512 * HD; i += PGSZ) {  // head W interleave
    int r = i >> 10, k = i & 1023;
    int dr = (r < 256) ? (2 * r) : (2 * (r - 256) + 1);
    P.Wsp[(size_t)dr * 1024 + k] = __float2bfloat16(P.W_sp[i]);
    P.Wsq[(size_t)dr * 1024 + k] = __float2bfloat16(P.W_sq[i]);
  }
  for (int i = gtid; i < 512; i += PGSZ) {
    int dr = (i < 256) ? (2 * i) : (2 * (i - 256) + 1);
    P.bsp_ro[dr] = P.b_sp[i];
    P.bsq_ro[dr] = P.b_sq[i];
  }
  for (int i = gtid; i < NT * NB * 320; i += PGSZ) {  // [act(32)|me(256)|pad(32)]
    int tb = i / 320, j = i - tb * 320;
    float v = (j < 32) ? P.actions[(size_t)tb * 32 + j]
                       : (j < 288 ? P.me[(size_t)tb * 256 + (j - 32)] : 0.0f);
    P.actme[i] = __float2bfloat16(v);
  }
  for (int i = gtid; i < NB * 1280; i += PGSZ) {  // obsmp(0)
    int bb = i / 1280, j = i - bb * 1280;
    float v = (j < ED) ? P.observations[(size_t)bb * ED + j] : P.mp[(size_t)bb * MD + (j - ED)];
    P.obsmp[i] = __float2bfloat16(v);
  }
  for (int i = gtid; i < NB * SD; i += PGSZ) {
    int r = i >> 8;
    P.sprev[i] = __float2bfloat16(P.prev_state[i] * P.nonterminals[r]);
  }
  for (int i = gtid; i < NB * BD; i += PGSZ) P.bel[i] = __float2bfloat16(P.prev_belief[i]);
}

// ---------------- mega: M-partitioned by PHYSICAL XCD, per-XCD barriers ----------------
__global__ __launch_bounds__(256, 4) void mega(Args P) {
  __shared__ alignas(16) char lds[32768];
  __shared__ int sh[3];
  const int tid = threadIdx.x;

  // self-organize: physical XCD id + slot within XCD
  if (tid == 0) {
    unsigned x;
    asm volatile("s_getreg_b32 %0, hwreg(HW_REG_XCC_ID)" : "=s"(x));
    x &= 7u;
    unsigned s = __hip_atomic_fetch_add(P.cnt + x * 16, 1u, __ATOMIC_RELAXED,
                                        __HIP_MEMORY_SCOPE_AGENT);
    sh[0] = (int)x;
    sh[1] = (int)s;
  }
  __syncthreads();
  const int xcd = sh[0], slot = sh[1];

  // one global barrier so all slot-claims are done, then read per-XCD count
  if (tid == 0) {
    __hip_atomic_fetch_add(P.cnt + 128, 1u, __ATOMIC_RELAXED, __HIP_MEMORY_SCOPE_AGENT);
    while (__hip_atomic_load(P.cnt + 128, __ATOMIC_RELAXED, __HIP_MEMORY_SCOPE_AGENT) <
           (unsigned)NBLK)
      __builtin_amdgcn_s_sleep(4);
    sh[2] = (int)__hip_atomic_load(P.cnt + xcd * 16, __ATOMIC_RELAXED,
                                   __HIP_MEMORY_SCOPE_AGENT);
  }
  __syncthreads();
  const int nx = sh[2];
  const int m0 = xcd * 64;                 // this XCD's 64 batch rows, all phases
  const size_t o_ps = (size_t)NT * NB * BD;
  const size_t blk = (size_t)NT * NB * SD;

  for (int t = 0; t < NT; ++t) {
    const int inst = t * 5;
    // ---- A: hid (16 tiles, 9 it) || gh (48 tiles, 16 it) ----
    for (int tt = slot; tt < 64; tt += nx) {
      if (tt < 16) {
        const int n = tt;
        gemm64(1, lds, P.sprev, SD, P.actme + (size_t)t * NB * 320, 320, 256,
               P.Wsa + (size_t)n * 64 * 576, 576, 9,
               P.b_sa + n * 64, nullptr, nullptr, P.hid + n * 64, BD, m0);
      } else {
        const int n = tt - 16;
        gemm64(0, lds, P.bel, BD, nullptr, 0, K1BIG,
               P.Whh + (size_t)n * 64 * BD, BD, 16,
               P.b_hh + n * 64, nullptr, P.gh + n * 64, nullptr, 3 * BD, m0);
      }
    }
    xbar(P.cnt, inst + 0, xcd, nx);
    // ---- B: gi (48 tiles, 16 it) || hq_obs (16 tiles, 20 it) ----
    for (int tt = slot; tt < 64; tt += nx) {
      if (tt < 48) {
        const int n = tt;
        gemm64(0, lds, P.hid, BD, nullptr, 0, K1BIG,
               P.Wih + (size_t)n * 64 * BD, BD, 16,
               P.b_ih + n * 64, nullptr, P.gi + n * 64, nullptr, 3 * BD, m0);
      } else {
        const int n = tt - 48;
        gemm64(0, lds, P.obsmp, 1280, nullptr, 0, K1BIG,
               P.Wbq + (size_t)n * 64 * 2304 + 1024, 2304, 20,
               nullptr, nullptr, P.hq_obs + n * 64, nullptr, 1024, m0);
      }
    }
    xbar(P.cnt, inst + 1, xcd, nx);
    // ---- C: GRU pointwise (rows m0..m0+63) + obsmp(t+1) pack ----
    for (int u = slot * 256 + tid; u < 8192; u += nx * 256) {
      const int r = m0 + (u >> 7), j0 = (u & 127) << 3;
      const float* gib = P.gi + (size_t)r * 3072 + j0;
      const float* ghb = P.gh + (size_t)r * 3072 + j0;
      f32x4 ir0, ir1, iz0, iz1, in0, in1, hr0, hr1, hz0, hz1, hn0, hn1, hbv;
      aload16(gib, &ir0);
      aload16(gib + 4, &ir1);
      aload16(gib + 1024, &iz0);
      aload16(gib + 1028, &iz1);
      aload16(gib + 2048, &in0);
      aload16(gib + 2052, &in1);
      aload16(ghb, &hr0);
      aload16(ghb + 4, &hr1);
      aload16(ghb + 1024, &hz0);
      aload16(ghb + 1028, &hz1);
      aload16(ghb + 2048, &hn0);
      aload16(ghb + 2052, &hn1);
      aload16(P.bel + (size_t)r * BD + j0, &hbv);
      VMWAIT(0)
      bf16x8 hb = __builtin_bit_cast(bf16x8, hbv);
      float o[8];
      unsigned short nb[8];
#pragma unroll
      for (int k = 0; k < 8; ++k) {
        float gr = (k < 4 ? ir0[k] : ir1[k - 4]) + (k < 4 ? hr0[k] : hr1[k - 4]);
        float gz = (k < 4 ? iz0[k] : iz1[k - 4]) + (k < 4 ? hz0[k] : hz1[k - 4]);
        float hn = (k < 4 ? hn0[k] : hn1[k - 4]);
        float in_ = (k < 4 ? in0[k] : in1[k - 4]);
        float r_ = sigmoidf_(gr);
        float z_ = sigmoidf_(gz);
        float n_ = tanhf(in_ + r_ * hn);
        __hip_bfloat16 hv16 = __builtin_bit_cast(__hip_bfloat16, (unsigned short)hb[k]);
        float hv = __bfloat162float(hv16);
        float bel = (1.0f - z_) * n_ + z_ * hv;
        o[k] = bel;
        nb[k] = bfb(bel);
      }
      float* ob = P.out + (size_t)t * NB * BD + (size_t)r * BD + j0;
      ntstore16(ob, f32x4{o[0], o[1], o[2], o[3]});
      ntstore16(ob + 4, f32x4{o[4], o[5], o[6], o[7]});
      astore16(P.bel + (size_t)r * BD + j0, __builtin_bit_cast(f32x4, *(bf16x8*)nb));
    }
    if (t + 1 < NT) {
      for (int v = slot * 256 + tid; v < 5120; v += nx * 256) {
        const int r = m0 + v / 80, c0 = (v % 80) << 4;
        const float* src = (c0 < ED)
            ? (P.observations + (size_t)(t + 1) * NB * ED + (size_t)r * ED + c0)
            : (P.mp + (size_t)(t + 1) * NB * MD + (size_t)r * MD + (c0 - ED));
        unsigned short nb[16];
#pragma unroll
        for (int q = 0; q < 4; ++q) {
          f32x4 vv = *(const f32x4*)(src + q * 4);
#pragma unroll
          for (int kk = 0; kk < 4; ++kk) nb[q * 4 + kk] = bfb(vv[kk]);
        }
        astore16(P.obsmp + (size_t)r * 1280 + c0, __builtin_bit_cast(f32x4, *(bf16x8*)nb));
        astore16(P.obsmp + (size_t)r * 1280 + c0 + 8,
                 __builtin_bit_cast(f32x4, *(bf16x8*)(nb + 8)));
      }
    }
    xbar(P.cnt, inst + 2, xcd, nx);
    // ---- D: hp (16 tiles) || hq = bel@Wbq[:1024] + hq_obs (16 tiles) ----
    for (int tt = slot; tt < 32; tt += nx) {
      if (tt < 16) {
        const int n = tt;
        gemm64(1, lds, P.bel, BD, nullptr, 0, K1BIG,
               P.Wbp + (size_t)n * 64 * BD, BD, 16,
               P.b_bp + n * 64, nullptr, nullptr, P.hpb + n * 64, HD, m0);
      } else {
        const int n = tt - 16;
        gemm64(3, lds, P.bel, BD, nullptr, 0, K1BIG,
               P.Wbq + (size_t)n * 64 * 2304, 2304, 16,
               P.b_bq + n * 64, P.hq_obs + n * 64, nullptr, P.hqb + n * 64, HD, m0);
      }
    }
    xbar(P.cnt, inst + 3, xcd, nx);
    // ---- E: p/q heads with fused epilogue + sprev carry ----
    {
      const float* ntn = P.nonterminals + (size_t)((t + 1 < NT) ? t + 1 : t) * NB;
      const size_t to = (size_t)t * NB * SD;
      for (int tt = slot; tt < 16; tt += nx) {
        if (tt < 8)
          gemm_head64(lds, P.hpb, P.Wsp + (size_t)tt * 64 * BD, P.bsp_ro,
                      P.noise_p + to, P.out + o_ps + to, P.out + o_ps + blk + to,
                      P.out + o_ps + 2 * blk + to, ntn, P.sprev, 0, tt * 64, m0);
        else
          gemm_head64(lds, P.hqb, P.Wsq + (size_t)(tt - 8) * 64 * BD, P.bsq_ro,
                      P.noise_q + to, P.out + o_ps + 3 * blk + to,
                      P.out + o_ps + 4 * blk + to, P.out + o_ps + 5 * blk + to,
                      ntn, P.sprev, 1, (tt - 8) * 64, m0);
      }
    }
    xbar(P.cnt, inst + 4, xcd, nx);
  }
}

// ---------------- host ----------------

extern "C" void kernel_launch(void* const* d_in, const int* in_sizes, int n_in,
                              void* d_out, int out_size, void* d_ws, size_t ws_size,
                              hipStream_t stream) {
  Args P;
  P.prev_state = (const float*)d_in[0];
  P.actions = (const float*)d_in[1];
  P.prev_belief = (const float*)d_in[2];
  P.observations = (const float*)d_in[3];
  P.nonterminals = (const float*)d_in[4];
  P.me = (const float*)d_in[5];
  P.mp = (const float*)d_in[6];
  P.noise_p = (const float*)d_in[7];
  P.noise_q = (const float*)d_in[8];
  P.W_sa = (const float*)d_in[9];  P.b_sa = (const float*)d_in[10];
  P.W_ih = (const float*)d_in[11]; P.b_ih = (const float*)d_in[12];
  P.W_hh = (const float*)d_in[13]; P.b_hh = (const float*)d_in[14];
  P.W_bp = (const float*)d_in[15]; P.b_bp = (const float*)d_in[16];
  P.W_sp = (const float*)d_in[17]; P.b_sp = (const float*)d_in[18];
  P.W_bq = (const float*)d_in[19]; P.b_bq = (const float*)d_in[20];
  P.W_sq = (const float*)d_in[21]; P.b_sq = (const float*)d_in[22];
  P.out = (float*)d_out;

  char* p = (char*)d_ws;
  auto carve = [&](size_t bytes) -> char* {
    char* r = p;
    p += (bytes + 255) & ~(size_t)255;
    return r;
  };
  const size_t cnt_bytes = (size_t)65536 * 4;  // slots + global + 250x8 barrier lines
  P.cnt = (unsigned*)carve(cnt_bytes);
  P.Wsa = (__hip_bfloat16*)carve((size_t)BD * 576 * 2);
  P.Wih = (__hip_bfloat16*)carve((size_t)3 * BD * BD * 2);
  P.Whh = (__hip_bfloat16*)carve((size_t)3 * BD * BD * 2);
  P.Wbp = (__hip_bfloat16*)carve((size_t)HD * BD * 2);
  P.Wbq = (__hip_bfloat16*)carve((size_t)HD * 2304 * 2);
  P.Wsp = (__hip_bfloat16*)carve((size_t)512 * HD * 2);
  P.Wsq = (__hip_bfloat16*)carve((size_t)512 * HD * 2);
  P.bsp_ro = (float*)carve(512 * 4);
  P.bsq_ro = (float*)carve(512 * 4);
  P.actme = (__hip_bfloat16*)carve((size_t)NT * NB * 320 * 2);
  P.obsmp = (__hip_bfloat16*)carve((size_t)NB * 1280 * 2);
  P.sprev = (__hip_bfloat16*)carve((size_t)NB * SD * 2);
  P.bel = (__hip_bfloat16*)carve((size_t)NB * BD * 2);
  P.hid = (__hip_bfloat16*)carve((size_t)NB * BD * 2);
  P.hpb = (__hip_bfloat16*)carve((size_t)NB * HD * 2);
  P.hqb = (__hip_bfloat16*)carve((size_t)NB * HD * 2);
  P.gi = (float*)carve((size_t)NB * 3 * BD * 4);
  P.gh = (float*)carve((size_t)NB * 3 * BD * 4);
  P.hq_obs = (float*)carve((size_t)NB * HD * 4);

  hipMemsetAsync(P.cnt, 0, cnt_bytes, stream);
  prep<<<1024, 256, 0, stream>>>(P);
  mega<<<NBLK, 256, 0, stream>>>(P);
}

// Round 9
// 5310.794 us; speedup vs baseline: 9.4278x; 1.0333x over previous
//
#include <hip/hip_runtime.h>
#include <hip/hip_bf16.h>

#define NT 50
#define NB 512
#define SD 256
#define BD 1024
#define HD 1024
#define ED 1024
#define MD 256
#define NBLK 512
#define PGSZ (1024 * 256)
#define K1BIG 0x40000000

typedef __attribute__((ext_vector_type(8))) short bf16x8;
typedef __attribute__((ext_vector_type(4))) float f32x4;

// W: plain cached (L1+L2+L3) -- read-only weights
__device__ __forceinline__ void gload_lds16(const void* g, void* l) {
  __builtin_amdgcn_global_load_lds(
      (const __attribute__((address_space(1))) void*)g,
      (__attribute__((address_space(3))) void*)l, 16, 0, 0);
}
// A: sc0 (aux=1) -- bypass L1, read fresh from XCD-local L2
__device__ __forceinline__ void gload_lds16_sc0(const void* g, void* l) {
  __builtin_amdgcn_global_load_lds(
      (const __attribute__((address_space(1))) void*)g,
      (__attribute__((address_space(3))) void*)l, 16, 0, 1);
}

// ---- XCD-local (sc0) activation access ----
__device__ __forceinline__ void aload16(const void* a, f32x4* r) {
  asm volatile("global_load_dwordx4 %0, %1, off sc0" : "=&v"(*r) : "v"(a) : "memory");
}
__device__ __forceinline__ void aload4(const void* a, float* r) {
  asm volatile("global_load_dword %0, %1, off sc0" : "=&v"(*r) : "v"(a) : "memory");
}
#define VMWAIT(N)                                        \
  asm volatile("s_waitcnt vmcnt(" #N ")" ::: "memory");  \
  __builtin_amdgcn_sched_barrier(0);

__device__ __forceinline__ void astore16(void* g, f32x4 v) {
  asm volatile("global_store_dwordx4 %0, %1, off sc0" :: "v"(g), "v"(v) : "memory");
}
__device__ __forceinline__ void astore4(void* g, float v) {
  asm volatile("global_store_dword %0, %1, off sc0" :: "v"(g), "v"(v) : "memory");
}
__device__ __forceinline__ void astore2(void* g, unsigned v) {
  asm volatile("global_store_short %0, %1, off sc0" :: "v"(g), "v"(v) : "memory");
}
__device__ __forceinline__ void ntstore16(void* g, f32x4 v) {
  asm volatile("global_store_dwordx4 %0, %1, off nt" :: "v"(g), "v"(v) : "memory");
}
__device__ __forceinline__ void ntstore4(void* g, float v) {
  asm volatile("global_store_dword %0, %1, off nt" :: "v"(g), "v"(v) : "memory");
}

__device__ __forceinline__ float sigmoidf_(float x) { return 1.0f / (1.0f + __expf(-x)); }
__device__ __forceinline__ float softplusf_(float x) {
  return (x > 0.0f) ? (x + log1pf(__expf(-x))) : log1pf(__expf(x));
}
__device__ __forceinline__ unsigned short bfb(float x) {
  __hip_bfloat16 h = __float2bfloat16(x);
  return __builtin_bit_cast(unsigned short, h);
}

// ---- per-XCD barrier ----
__device__ __forceinline__ void xbar(unsigned* cnt, int inst, int xcd, int nx) {
  asm volatile("s_waitcnt vmcnt(0) lgkmcnt(0)" ::: "memory");
  __syncthreads();
  if (threadIdx.x == 0) {
    unsigned* c = cnt + 256 + (size_t)(inst * 8 + xcd) * 16;
    __hip_atomic_fetch_add(c, 1u, __ATOMIC_RELAXED, __HIP_MEMORY_SCOPE_AGENT);
    while (__hip_atomic_load(c, __ATOMIC_RELAXED, __HIP_MEMORY_SCOPE_AGENT) < (unsigned)nx)
      __builtin_amdgcn_s_sleep(2);
  }
  __syncthreads();
}

// ---- 64x64 GEMM tile, BK=64, RING-3 LDS, all-gload_lds staging, counted vmcnt ----
// Per stage: A 8KB (sc0) + W 8KB (cached). Never drain vmcnt to 0 mid-loop.
// EPI: 0 fp32(+bias); 1 relu->bf16(+bias); 3 relu->bf16(+bias+Cadd).
__device__ __noinline__ void gemm64(
    int EPI, char* lds,
    const __hip_bfloat16* __restrict__ A1, int lda1,
    const __hip_bfloat16* __restrict__ A2, int lda2, int K1,
    const __hip_bfloat16* __restrict__ Wr, int ldw, int nIter,
    const float* __restrict__ bias, const float* __restrict__ Cadd,
    float* __restrict__ Cf, __hip_bfloat16* __restrict__ Cb, int ldc, int m0) {
  const int tid = threadIdx.x;
  const int lane = tid & 63, w = tid >> 6;
  const int wr = w >> 1, wc = w & 1;
  f32x4 acc[2][2] = {};
  const __hip_bfloat16* a1r = A1 + (size_t)(m0 + lane) * lda1;
  const __hip_bfloat16* a2r = A2 ? (A2 + (size_t)(m0 + lane) * lda2) : a1r;
  const __hip_bfloat16* wrow = Wr + (size_t)lane * ldw;

  auto stage = [&](int it) {
    const int k0 = it << 6;
    char* la = lds + (size_t)(it % 3) * 16384;
    char* lb = la + 8192;
    const __hip_bfloat16* as = (k0 < K1) ? (a1r + k0) : (a2r + (k0 - K1));
    gload_lds16_sc0(as + (2 * w) * 8, la + (2 * w) * 1024);
    gload_lds16_sc0(as + (2 * w + 1) * 8, la + (2 * w + 1) * 1024);
    gload_lds16(wrow + k0 + (2 * w) * 8, lb + (2 * w) * 1024);
    gload_lds16(wrow + k0 + (2 * w + 1) * 8, lb + (2 * w + 1) * 1024);
  };

  __syncthreads();  // entry: LDS reuse guard (full drain once per call)
  stage(0);
  stage(1);
  VMWAIT(4)         // stage(0) landed; stage(1) stays in flight
  __builtin_amdgcn_s_barrier();
  __builtin_amdgcn_sched_barrier(0);

  const int kq = lane >> 4, r15 = lane & 15;
  for (int i = 0; i < nIter; ++i) {
    if (i + 2 < nIter) stage(i + 2);
    const char* la = lds + (size_t)(i % 3) * 16384;
    const char* lb = la + 8192;
#pragma unroll
    for (int s = 0; s < 2; ++s) {
      bf16x8 af[2], bfr[2];
#pragma unroll
      for (int m = 0; m < 2; ++m)
        af[m] = *(const bf16x8*)(la + (size_t)((s * 4 + kq) * 64 + wr * 32 + m * 16 + r15) * 16);
#pragma unroll
      for (int n = 0; n < 2; ++n)
        bfr[n] = *(const bf16x8*)(lb + (size_t)((s * 4 + kq) * 64 + wc * 32 + n * 16 + r15) * 16);
#pragma unroll
      for (int m = 0; m < 2; ++m)
#pragma unroll
        for (int n = 0; n < 2; ++n)
          acc[m][n] = __builtin_amdgcn_mfma_f32_16x16x32_bf16(af[m], bfr[n], acc[m][n], 0, 0, 0);
    }
    if (i + 1 < nIter) {
      if (i + 2 < nIter) {
        VMWAIT(4)   // forces stage(i+1); stage(i+2) remains in flight
      } else {
        VMWAIT(0)   // tail: nothing newer was issued
      }
      __builtin_amdgcn_s_barrier();
      __builtin_amdgcn_sched_barrier(0);
    }
  }

  const int rg = lane >> 4;
  float ad[2][2][4];
  if (EPI == 3) {
#pragma unroll
    for (int m = 0; m < 2; ++m)
#pragma unroll
      for (int n = 0; n < 2; ++n) {
        const int col = wc * 32 + n * 16 + r15;
#pragma unroll
        for (int i2 = 0; i2 < 4; ++i2) {
          const int row = m0 + wr * 32 + m * 16 + rg * 4 + i2;
          aload4(Cadd + (size_t)row * ldc + col, &ad[m][n][i2]);
        }
      }
    VMWAIT(0)
  }
#pragma unroll
  for (int m = 0; m < 2; ++m) {
#pragma unroll
    for (int n = 0; n < 2; ++n) {
      const int col = wc * 32 + n * 16 + r15;
      const float bv = bias ? bias[col] : 0.0f;
#pragma unroll
      for (int i2 = 0; i2 < 4; ++i2) {
        const int row = m0 + wr * 32 + m * 16 + rg * 4 + i2;
        float v = acc[m][n][i2] + bv;
        if (EPI == 3) v += ad[m][n][i2];
        if (EPI != 0) {
          v = v > 0.0f ? v : 0.0f;
          astore2(Cb + (size_t)row * ldc + col, (unsigned)bfb(v));
        } else {
          astore4(Cf + (size_t)row * ldc + col, v);
        }
      }
    }
  }
}

// ---- head GEMM (K=1024) with fused prior/posterior epilogue; W pre-interleaved ----
__device__ __noinline__ void gemm_head64(
    char* lds, const __hip_bfloat16* __restrict__ A,
    const __hip_bfloat16* __restrict__ Wr, const float* __restrict__ bias,
    const float* __restrict__ noise, float* __restrict__ st_o, float* __restrict__ mn_o,
    float* __restrict__ sd_o, const float* __restrict__ ntn,
    __hip_bfloat16* __restrict__ sprev, int isq, int n0, int m0) {
  const int tid = threadIdx.x;
  const int lane = tid & 63, w = tid >> 6;
  const int wr = w >> 1, wc = w & 1;
  f32x4 acc[2][2] = {};
  const __hip_bfloat16* ar = A + (size_t)(m0 + lane) * BD;
  const __hip_bfloat16* wrow = Wr + (size_t)lane * BD;

  auto stage = [&](int it) {
    const int k0 = it << 6;
    char* la = lds + (size_t)(it % 3) * 16384;
    char* lb = la + 8192;
    gload_lds16_sc0(ar + k0 + (2 * w) * 8, la + (2 * w) * 1024);
    gload_lds16_sc0(ar + k0 + (2 * w + 1) * 8, la + (2 * w + 1) * 1024);
    gload_lds16(wrow + k0 + (2 * w) * 8, lb + (2 * w) * 1024);
    gload_lds16(wrow + k0 + (2 * w + 1) * 8, lb + (2 * w + 1) * 1024);
  };

  __syncthreads();
  stage(0);
  stage(1);
  VMWAIT(4)
  __builtin_amdgcn_s_barrier();
  __builtin_amdgcn_sched_barrier(0);

  const int kq = lane >> 4, r15 = lane & 15;
  for (int i = 0; i < 16; ++i) {
    if (i + 2 < 16) stage(i + 2);
    const char* la = lds + (size_t)(i % 3) * 16384;
    const char* lb = la + 8192;
#pragma unroll
    for (int s = 0; s < 2; ++s) {
      bf16x8 af[2], bfr[2];
#pragma unroll
      for (int m = 0; m < 2; ++m)
        af[m] = *(const bf16x8*)(la + (size_t)((s * 4 + kq) * 64 + wr * 32 + m * 16 + r15) * 16);
#pragma unroll
      for (int n = 0; n < 2; ++n)
        bfr[n] = *(const bf16x8*)(lb + (size_t)((s * 4 + kq) * 64 + wc * 32 + n * 16 + r15) * 16);
#pragma unroll
      for (int m = 0; m < 2; ++m)
#pragma unroll
        for (int n = 0; n < 2; ++n)
          acc[m][n] = __builtin_amdgcn_mfma_f32_16x16x32_bf16(af[m], bfr[n], acc[m][n], 0, 0, 0);
    }
    if (i + 1 < 16) {
      if (i + 2 < 16) {
        VMWAIT(4)
      } else {
        VMWAIT(0)
      }
      __builtin_amdgcn_s_barrier();
      __builtin_amdgcn_sched_barrier(0);
    }
  }

  const int rg = lane >> 4;
  const bool even = (r15 & 1) == 0;
#pragma unroll
  for (int m = 0; m < 2; ++m) {
#pragma unroll
    for (int n = 0; n < 2; ++n) {
      const int col = n0 + wc * 32 + n * 16 + r15;  // interleaved mean/raw
      const int j = col >> 1;
      const float bv = bias[col];
#pragma unroll
      for (int i2 = 0; i2 < 4; ++i2) {
        const int row = m0 + wr * 32 + m * 16 + rg * 4 + i2;
        float v = acc[m][n][i2] + bv;
        float partner = __shfl_xor(v, 1);
        float mean = even ? v : partner;
        float raw = even ? partner : v;
        float sd = fminf(softplusf_(raw) + 0.1f, 5.0f);
        const size_t o = (size_t)row * SD + j;
        if (even) {
          float st = mean + sd * noise[o];
          ntstore4(mn_o + o, mean);
          ntstore4(st_o + o, st);
          if (isq) astore2(sprev + o, (unsigned)bfb(st * ntn[row]));
        } else {
          ntstore4(sd_o + o, sd);
        }
      }
    }
  }
}

struct Args {
  const float *prev_state, *actions, *prev_belief, *observations, *nonterminals,
      *me, *mp, *noise_p, *noise_q,
      *W_sa, *b_sa, *W_ih, *b_ih, *W_hh, *b_hh,
      *W_bp, *b_bp, *W_sp, *b_sp, *W_bq, *b_bq, *W_sq, *b_sq;
  float* out;
  unsigned* cnt;
  __hip_bfloat16 *Wsa, *Wih, *Whh, *Wbp, *Wbq, *Wsp, *Wsq;
  __hip_bfloat16 *actme, *obsmp, *sprev, *bel, *hid, *hpb, *hqb;
  float *gi, *gh, *hq_obs;
  float *bsp_ro, *bsq_ro;
};

// ---------------- prep ----------------
__global__ __launch_bounds__(256) void prep(Args P) {
  const int gtid = blockIdx.x * 256 + threadIdx.x;
  for (int i = gtid; i < BD * 576; i += PGSZ) {  // W_sa padded K 544->576
    int r = i / 576, k = i - r * 576;
    P.Wsa[i] = __float2bfloat16(k < 544 ? P.W_sa[(size_t)r * 544 + k] : 0.0f);
  }
  for (int i = gtid; i < 3 * BD * BD; i += PGSZ) P.Wih[i] = __float2bfloat16(P.W_ih[i]);
  for (int i = gtid; i < 3 * BD * BD; i += PGSZ) P.Whh[i] = __float2bfloat16(P.W_hh[i]);
  for (int i = gtid; i < HD * BD; i += PGSZ) P.Wbp[i] = __float2bfloat16(P.W_bp[i]);
  for (int i = gtid; i < HD * 2304; i += PGSZ) P.Wbq[i] = __float2bfloat16(P.W_bq[i]);
  for (int i = gtid; i < 512 * HD; i += PGSZ) {  // head W interleave
    int r = i >> 10, k = i & 1023;
    int dr = (r < 256) ? (2 * r) : (2 * (r - 256) + 1);
    P.Wsp[(size_t)dr * 1024 + k] = __float2bfloat16(P.W_sp[i]);
    P.Wsq[(size_t)dr * 1024 + k] = __float2bfloat16(P.W_sq[i]);
  }
  for (int i = gtid; i < 512; i += PGSZ) {
    int dr = (i < 256) ? (2 * i) : (2 * (i - 256) + 1);
    P.bsp_ro[dr] = P.b_sp[i];
    P.bsq_ro[dr] = P.b_sq[i];
  }
  for (int i = gtid; i < NT * NB * 320; i += PGSZ) {  // [act(32)|me(256)|pad(32)]
    int tb = i / 320, j = i - tb * 320;
    float v = (j < 32) ? P.actions[(size_t)tb * 32 + j]
                       : (j < 288 ? P.me[(size_t)tb * 256 + (j - 32)] : 0.0f);
    P.actme[i] = __float2bfloat16(v);
  }
  for (int i = gtid; i < NB * 1280; i += PGSZ) {  // obsmp(0)
    int bb = i / 1280, j = i - bb * 1280;
    float v = (j < ED) ? P.observations[(size_t)bb * ED + j] : P.mp[(size_t)bb * MD + (j - ED)];
    P.obsmp[i] = __float2bfloat16(v);
  }
  for (int i = gtid; i < NB * SD; i += PGSZ) {
    int r = i >> 8;
    P.sprev[i] = __float2bfloat16(P.prev_state[i] * P.nonterminals[r]);
  }
  for (int i = gtid; i < NB * BD; i += PGSZ) P.bel[i] = __float2bfloat16(P.prev_belief[i]);
}

// ---------------- mega: M-partitioned by PHYSICAL XCD, per-XCD barriers ----------------
__global__ __launch_bounds__(256, 2) void mega(Args P) {
  __shared__ alignas(16) char lds[49152];
  __shared__ int sh[3];
  const int tid = threadIdx.x;

  if (tid == 0) {
    unsigned x;
    asm volatile("s_getreg_b32 %0, hwreg(HW_REG_XCC_ID)" : "=s"(x));
    x &= 7u;
    unsigned s = __hip_atomic_fetch_add(P.cnt + x * 16, 1u, __ATOMIC_RELAXED,
                                        __HIP_MEMORY_SCOPE_AGENT);
    sh[0] = (int)x;
    sh[1] = (int)s;
  }
  __syncthreads();
  const int xcd = sh[0], slot = sh[1];

  if (tid == 0) {
    __hip_atomic_fetch_add(P.cnt + 128, 1u, __ATOMIC_RELAXED, __HIP_MEMORY_SCOPE_AGENT);
    while (__hip_atomic_load(P.cnt + 128, __ATOMIC_RELAXED, __HIP_MEMORY_SCOPE_AGENT) <
           (unsigned)NBLK)
      __builtin_amdgcn_s_sleep(4);
    sh[2] = (int)__hip_atomic_load(P.cnt + xcd * 16, __ATOMIC_RELAXED,
                                   __HIP_MEMORY_SCOPE_AGENT);
  }
  __syncthreads();
  const int nx = sh[2];
  const int m0 = xcd * 64;
  const size_t o_ps = (size_t)NT * NB * BD;
  const size_t blk = (size_t)NT * NB * SD;

  for (int t = 0; t < NT; ++t) {
    const int inst = t * 5;
    // ---- A: hid (16 tiles, 9 it) || gh (48 tiles, 16 it) ----
    for (int tt = slot; tt < 64; tt += nx) {
      if (tt < 16) {
        const int n = tt;
        gemm64(1, lds, P.sprev, SD, P.actme + (size_t)t * NB * 320, 320, 256,
               P.Wsa + (size_t)n * 64 * 576, 576, 9,
               P.b_sa + n * 64, nullptr, nullptr, P.hid + n * 64, BD, m0);
      } else {
        const int n = tt - 16;
        gemm64(0, lds, P.bel, BD, nullptr, 0, K1BIG,
               P.Whh + (size_t)n * 64 * BD, BD, 16,
               P.b_hh + n * 64, nullptr, P.gh + n * 64, nullptr, 3 * BD, m0);
      }
    }
    xbar(P.cnt, inst + 0, xcd, nx);
    // ---- B: gi (48 tiles, 16 it) || hq_obs (16 tiles, 20 it) ----
    for (int tt = slot; tt < 64; tt += nx) {
      if (tt < 48) {
        const int n = tt;
        gemm64(0, lds, P.hid, BD, nullptr, 0, K1BIG,
               P.Wih + (size_t)n * 64 * BD, BD, 16,
               P.b_ih + n * 64, nullptr, P.gi + n * 64, nullptr, 3 * BD, m0);
      } else {
        const int n = tt - 48;
        gemm64(0, lds, P.obsmp, 1280, nullptr, 0, K1BIG,
               P.Wbq + (size_t)n * 64 * 2304 + 1024, 2304, 20,
               nullptr, nullptr, P.hq_obs + n * 64, nullptr, 1024, m0);
      }
    }
    xbar(P.cnt, inst + 1, xcd, nx);
    // ---- C: GRU pointwise (rows m0..m0+63) + obsmp(t+1) pack ----
    for (int u = slot * 256 + tid; u < 8192; u += nx * 256) {
      const int r = m0 + (u >> 7), j0 = (u & 127) << 3;
      const float* gib = P.gi + (size_t)r * 3072 + j0;
      const float* ghb = P.gh + (size_t)r * 3072 + j0;
      f32x4 ir0, ir1, iz0, iz1, in0, in1, hr0, hr1, hz0, hz1, hn0, hn1, hbv;
      aload16(gib, &ir0);
      aload16(gib + 4, &ir1);
      aload16(gib + 1024, &iz0);
      aload16(gib + 1028, &iz1);
      aload16(gib + 2048, &in0);
      aload16(gib + 2052, &in1);
      aload16(ghb, &hr0);
      aload16(ghb + 4, &hr1);
      aload16(ghb + 1024, &hz0);
      aload16(ghb + 1028, &hz1);
      aload16(ghb + 2048, &hn0);
      aload16(ghb + 2052, &hn1);
      aload16(P.bel + (size_t)r * BD + j0, &hbv);
      VMWAIT(0)
      bf16x8 hb = __builtin_bit_cast(bf16x8, hbv);
      float o[8];
      unsigned short nb[8];
#pragma unroll
      for (int k = 0; k < 8; ++k) {
        float gr = (k < 4 ? ir0[k] : ir1[k - 4]) + (k < 4 ? hr0[k] : hr1[k - 4]);
        float gz = (k < 4 ? iz0[k] : iz1[k - 4]) + (k < 4 ? hz0[k] : hz1[k - 4]);
        float hn = (k < 4 ? hn0[k] : hn1[k - 4]);
        float in_ = (k < 4 ? in0[k] : in1[k - 4]);
        float r_ = sigmoidf_(gr);
        float z_ = sigmoidf_(gz);
        float n_ = tanhf(in_ + r_ * hn);
        __hip_bfloat16 hv16 = __builtin_bit_cast(__hip_bfloat16, (unsigned short)hb[k]);
        float hv = __bfloat162float(hv16);
        float bel = (1.0f - z_) * n_ + z_ * hv;
        o[k] = bel;
        nb[k] = bfb(bel);
      }
      float* ob = P.out + (size_t)t * NB * BD + (size_t)r * BD + j0;
      ntstore16(ob, f32x4{o[0], o[1], o[2], o[3]});
      ntstore16(ob + 4, f32x4{o[4], o[5], o[6], o[7]});
      astore16(P.bel + (size_t)r * BD + j0, __builtin_bit_cast(f32x4, *(bf16x8*)nb));
    }
    if (t + 1 < NT) {
      for (int v = slot * 256 + tid; v < 5120; v += nx * 256) {
        const int r = m0 + v / 80, c0 = (v % 80) << 4;
        const float* src = (c0 < ED)
            ? (P.observations + (size_t)(t + 1) * NB * ED + (size_t)r * ED + c0)
            : (P.mp + (size_t)(t + 1) * NB * MD + (size_t)r * MD + (c0 - ED));
        unsigned short nb[16];
#pragma unroll
        for (int q = 0; q < 4; ++q) {
          f32x4 vv = *(const f32x4*)(src + q * 4);
#pragma unroll
          for (int kk = 0; kk < 4; ++kk) nb[q * 4 + kk] = bfb(vv[kk]);
        }
        astore16(P.obsmp + (size_t)r * 1280 + c0, __builtin_bit_cast(f32x4, *(bf16x8*)nb));
        astore16(P.obsmp + (size_t)r * 1280 + c0 + 8,
                 __builtin_bit_cast(f32x4, *(bf16x8*)(nb + 8)));
      }
    }
    xbar(P.cnt, inst + 2, xcd, nx);
    // ---- D: hp (16 tiles) || hq = bel@Wbq[:1024] + hq_obs (16 tiles) ----
    for (int tt = slot; tt < 32; tt += nx) {
      if (tt < 16) {
        const int n = tt;
        gemm64(1, lds, P.bel, BD, nullptr, 0, K1BIG,
               P.Wbp + (size_t)n * 64 * BD, BD, 16,
               P.b_bp + n * 64, nullptr, nullptr, P.hpb + n * 64, HD, m0);
      } else {
        const int n = tt - 16;
        gemm64(3, lds, P.bel, BD, nullptr, 0, K1BIG,
               P.Wbq + (size_t)n * 64 * 2304, 2304, 16,
               P.b_bq + n * 64, P.hq_obs + n * 64, nullptr, P.hqb + n * 64, HD, m0);
      }
    }
    xbar(P.cnt, inst + 3, xcd, nx);
    // ---- E: p/q heads with fused epilogue + sprev carry ----
    {
      const float* ntn = P.nonterminals + (size_t)((t + 1 < NT) ? t + 1 : t) * NB;
      const size_t to = (size_t)t * NB * SD;
      for (int tt = slot; tt < 16; tt += nx) {
        if (tt < 8)
          gemm_head64(lds, P.hpb, P.Wsp + (size_t)tt * 64 * BD, P.bsp_ro,
                      P.noise_p + to, P.out + o_ps + to, P.out + o_ps + blk + to,
                      P.out + o_ps + 2 * blk + to, ntn, P.sprev, 0, tt * 64, m0);
        else
          gemm_head64(lds, P.hqb, P.Wsq + (size_t)(tt - 8) * 64 * BD, P.bsq_ro,
                      P.noise_q + to, P.out + o_ps + 3 * blk + to,
                      P.out + o_ps + 4 * blk + to, P.out + o_ps + 5 * blk + to,
                      ntn, P.sprev, 1, (tt - 8) * 64, m0);
      }
    }
    xbar(P.cnt, inst + 4, xcd, nx);
  }
}

// ---------------- host ----------------

extern "C" void kernel_launch(void* const* d_in, const int* in_sizes, int n_in,
                              void* d_out, int out_size, void* d_ws, size_t ws_size,
                              hipStream_t stream) {
  Args P;
  P.prev_state = (const float*)d_in[0];
  P.actions = (const float*)d_in[1];
  P.prev_belief = (const float*)d_in[2];
  P.observations = (const float*)d_in[3];
  P.nonterminals = (const float*)d_in[4];
  P.me = (const float*)d_in[5];
  P.mp = (const float*)d_in[6];
  P.noise_p = (const float*)d_in[7];
  P.noise_q = (const float*)d_in[8];
  P.W_sa = (const float*)d_in[9];  P.b_sa = (const float*)d_in[10];
  P.W_ih = (const float*)d_in[11]; P.b_ih = (const float*)d_in[12];
  P.W_hh = (const float*)d_in[13]; P.b_hh = (const float*)d_in[14];
  P.W_bp = (const float*)d_in[15]; P.b_bp = (const float*)d_in[16];
  P.W_sp = (const float*)d_in[17]; P.b_sp = (const float*)d_in[18];
  P.W_bq = (const float*)d_in[19]; P.b_bq = (const float*)d_in[20];
  P.W_sq = (const float*)d_in[21]; P.b_sq = (const float*)d_in[22];
  P.out = (float*)d_out;

  char* p = (char*)d_ws;
  auto carve = [&](size_t bytes) -> char* {
    char* r = p;
    p += (bytes + 255) & ~(size_t)255;
    return r;
  };
  const size_t cnt_bytes = (size_t)65536 * 4;
  P.cnt = (unsigned*)carve(cnt_bytes);
  P.Wsa = (__hip_bfloat16*)carve((size_t)BD * 576 * 2);
  P.Wih = (__hip_bfloat16*)carve((size_t)3 * BD * BD * 2);
  P.Whh = (__hip_bfloat16*)carve((size_t)3 * BD * BD * 2);
  P.Wbp = (__hip_bfloat16*)carve((size_t)HD * BD * 2);
  P.Wbq = (__hip_bfloat16*)carve((size_t)HD * 2304 * 2);
  P.Wsp = (__hip_bfloat16*)carve((size_t)512 * HD * 2);
  P.Wsq = (__hip_bfloat16*)carve((size_t)512 * HD * 2);
  P.bsp_ro = (float*)carve(512 * 4);
  P.bsq_ro = (float*)carve(512 * 4);
  P.actme = (__hip_bfloat16*)carve((size_t)NT * NB * 320 * 2);
  P.obsmp = (__hip_bfloat16*)carve((size_t)NB * 1280 * 2);
  P.sprev = (__hip_bfloat16*)carve((size_t)NB * SD * 2);
  P.bel = (__hip_bfloat16*)carve((size_t)NB * BD * 2);
  P.hid = (__hip_bfloat16*)carve((size_t)NB * BD * 2);
  P.hpb = (__hip_bfloat16*)carve((size_t)NB * HD * 2);
  P.hqb = (__hip_bfloat16*)carve((size_t)NB * HD * 2);
  P.gi = (float*)carve((size_t)NB * 3 * BD * 4);
  P.gh = (float*)carve((size_t)NB * 3 * BD * 4);
  P.hq_obs = (float*)carve((size_t)NB * HD * 4);

  hipMemsetAsync(P.cnt, 0, cnt_bytes, stream);
  prep<<<1024, 256, 0, stream>>>(P);
  mega<<<NBLK, 256, 0, stream>>>(P);
}